// Round 1
// 2699.326 us; speedup vs baseline: 1.5592x; 1.5592x over previous
//
#include <hip/hip_runtime.h>

#define S_LEN 8192
#define HID 2048
#define HKN 8
#define HVN 16
#define DKD 128
#define DVD 128
#define NCHUNK 128
#define CLEN 64
#define NQKV 4096
#define EPSF 1e-6f

typedef unsigned int u32;
typedef unsigned short u16;
typedef __attribute__((ext_vector_type(8))) short s16x8;
typedef __attribute__((ext_vector_type(4))) float f32x4;

__device__ __forceinline__ float bfraw2f(u16 v) { return __uint_as_float(((u32)v) << 16); }
__device__ __forceinline__ u16 f2bf_rne(float f) {
    u32 u = __float_as_uint(f);
    u32 r = u + 0x7fffu + ((u >> 16) & 1u);
    return (u16)(r >> 16);
}
__device__ __forceinline__ void unpack8(uint4 u, float* f) {
    const u32 a[4] = {u.x, u.y, u.z, u.w};
#pragma unroll
    for (int q = 0; q < 4; ++q) {
        f[2*q]   = __uint_as_float(a[q] << 16);
        f[2*q+1] = __uint_as_float(a[q] & 0xffff0000u);
    }
}
__device__ __forceinline__ uint4 pack8(const float* v) {
    uint4 r;
    r.x = (u32)f2bf_rne(v[0]) | ((u32)f2bf_rne(v[1]) << 16);
    r.y = (u32)f2bf_rne(v[2]) | ((u32)f2bf_rne(v[3]) << 16);
    r.z = (u32)f2bf_rne(v[4]) | ((u32)f2bf_rne(v[5]) << 16);
    r.w = (u32)f2bf_rne(v[6]) | ((u32)f2bf_rne(v[7]) << 16);
    return r;
}

// async global->LDS staging (lane-strided 16B; LDS dest wave-uniform base + lane*16)
__device__ __forceinline__ void gload_lds16(const u16* g, u16* l) {
    __builtin_amdgcn_global_load_lds((const __attribute__((address_space(1))) unsigned int*)g,
                                     (__attribute__((address_space(3))) unsigned int*)l, 16, 0, 0);
}
__device__ __forceinline__ void gload_lds4(const float* g, u16* l) {
    __builtin_amdgcn_global_load_lds((const __attribute__((address_space(1))) unsigned int*)g,
                                     (__attribute__((address_space(3))) unsigned int*)l, 4, 0, 0);
}

// ------------- b,a projections (scalar, broadcast-x) + activations -------------
__global__ __launch_bounds__(256) void ba_kernel(const float* __restrict__ x,
                                                 const float* __restrict__ Wb,
                                                 const float* __restrict__ Wa,
                                                 const float* __restrict__ A_log,
                                                 const float* __restrict__ dt_bias,
                                                 float* __restrict__ beta,
                                                 float* __restrict__ g) {
    const int t = threadIdx.x;
    const int row = blockIdx.x * 8 + (t >> 5);
    const int c = t & 31;
    const int cc = c & 15;
    const float* W = (c < 16) ? Wb : Wa;
    const float* xr = x + (size_t)row * HID;
    float acc = 0.f;
    for (int k = 0; k < HID; ++k) acc = fmaf(xr[k], W[k * 16 + cc], acc);
    if (c < 16) {
        beta[row * 16 + cc] = 1.f / (1.f + expf(-acc));
    } else {
        float v = acc + dt_bias[cc];
        float sp = (v > 20.f) ? v : log1pf(expf(v));
        g[row * 16 + cc] = -expf(A_log[cc]) * sp;
    }
}

// ------------- MFMA GEMM: C[M,N] = A[M,K] * B[K,N], B fp32 row-major [K,N] -------------
template <int AF32, int F32OUT>
__global__ __launch_bounds__(256) void gemm_kn(const void* __restrict__ Av,
                                               const float* __restrict__ B,
                                               void* __restrict__ Cv,
                                               int M, int N, int K) {
    __shared__ u16 As[128 * 72];
    __shared__ u16 Bs[128 * 72];
    const int t = threadIdx.x;
    const int n0 = blockIdx.x * 128;
    const int m0 = blockIdx.y * 128;
    const int w = t >> 6, lane = t & 63;
    const int wm = (w >> 1) * 64, wn = (w & 1) * 64;
    const int ml = lane & 15, kq = lane >> 4;
    f32x4 acc[4][4];
#pragma unroll
    for (int i = 0; i < 4; ++i)
#pragma unroll
        for (int j = 0; j < 4; ++j) acc[i][j] = (f32x4){0.f, 0.f, 0.f, 0.f};

    const int nkt = K >> 6;
    for (int kt = 0; kt < nkt; ++kt) {
        const int k0 = kt << 6;
        if (AF32) {
            const float* A = (const float*)Av;
#pragma unroll
            for (int i = 0; i < 8; ++i) {
                int flat = i * 256 + t;
                int row = flat >> 4, kc = (flat & 15) << 2;
                float4 v = *(const float4*)(A + (size_t)(m0 + row) * K + k0 + kc);
                uint2 r;
                r.x = (u32)f2bf_rne(v.x) | ((u32)f2bf_rne(v.y) << 16);
                r.y = (u32)f2bf_rne(v.z) | ((u32)f2bf_rne(v.w) << 16);
                *(uint2*)(As + row * 72 + kc) = r;
            }
        } else {
            const u16* A = (const u16*)Av;
#pragma unroll
            for (int i = 0; i < 4; ++i) {
                int flat = i * 256 + t;
                int row = flat >> 3, kc = (flat & 7) << 3;
                *(uint4*)(As + row * 72 + kc) = *(const uint4*)(A + (size_t)(m0 + row) * K + k0 + kc);
            }
        }
#pragma unroll
        for (int i = 0; i < 8; ++i) {
            int flat = i * 256 + t;
            int kr = flat >> 5, nc = (flat & 31) << 2;
            float4 v = *(const float4*)(B + (size_t)(k0 + kr) * N + n0 + nc);
            Bs[(nc + 0) * 72 + kr] = f2bf_rne(v.x);
            Bs[(nc + 1) * 72 + kr] = f2bf_rne(v.y);
            Bs[(nc + 2) * 72 + kr] = f2bf_rne(v.z);
            Bs[(nc + 3) * 72 + kr] = f2bf_rne(v.w);
        }
        __syncthreads();
#pragma unroll
        for (int ks = 0; ks < 2; ++ks) {
            s16x8 af[4], bfr[4];
#pragma unroll
            for (int mt = 0; mt < 4; ++mt)
                af[mt] = *(const s16x8*)(As + (wm + mt * 16 + ml) * 72 + ks * 32 + kq * 8);
#pragma unroll
            for (int nt = 0; nt < 4; ++nt)
                bfr[nt] = *(const s16x8*)(Bs + (wn + nt * 16 + ml) * 72 + ks * 32 + kq * 8);
#pragma unroll
            for (int mt = 0; mt < 4; ++mt)
#pragma unroll
                for (int nt = 0; nt < 4; ++nt)
                    acc[mt][nt] = __builtin_amdgcn_mfma_f32_16x16x32_bf16(af[mt], bfr[nt], acc[mt][nt], 0, 0, 0);
        }
        __syncthreads();
    }
#pragma unroll
    for (int mt = 0; mt < 4; ++mt)
#pragma unroll
        for (int nt = 0; nt < 4; ++nt)
#pragma unroll
            for (int r = 0; r < 4; ++r) {
                int row = m0 + wm + mt * 16 + kq * 4 + r;
                int col = n0 + wn + nt * 16 + ml;
                float v = acc[mt][nt][r];
                if (F32OUT)
                    ((float*)Cv)[(size_t)row * N + col] = v;
                else
                    ((u16*)Cv)[(size_t)row * N + col] = f2bf_rne(v);
            }
}

// ------------- conv(K=4) + silu + l2norm + beta-fold prep -------------
__global__ __launch_bounds__(512) void prep_kernel(const u16* __restrict__ Cmix,
                                                   const float* __restrict__ conv_w,
                                                   const float* __restrict__ beta,
                                                   u16* __restrict__ qn,
                                                   u16* __restrict__ kn,
                                                   u16* __restrict__ vb) {
    const int s = blockIdx.x;
    const int t = threadIdx.x;
    const int c8 = t << 3;
    __shared__ float ssq[16];
    if (t < 16) ssq[t] = 0.f;

    float y[8];
#pragma unroll
    for (int i = 0; i < 8; ++i) y[i] = 0.f;
    {
        uint4 mrow[4];
#pragma unroll
        for (int j = 0; j < 4; ++j) {
            int r = s - 3 + j;
            if (r >= 0) mrow[j] = *(const uint4*)(Cmix + (size_t)r * NQKV + c8);
            else        mrow[j] = uint4{0u, 0u, 0u, 0u};
        }
        float cw[8][4];
#pragma unroll
        for (int i = 0; i < 8; ++i) {
            float4 cv = *(const float4*)(conv_w + (size_t)(c8 + i) * 4);
            cw[i][0] = cv.x; cw[i][1] = cv.y; cw[i][2] = cv.z; cw[i][3] = cv.w;
        }
#pragma unroll
        for (int j = 0; j < 4; ++j) {
            float mf[8];
            unpack8(mrow[j], mf);
#pragma unroll
            for (int i = 0; i < 8; ++i) y[i] = fmaf(mf[i], cw[i][j], y[i]);
        }
#pragma unroll
        for (int i = 0; i < 8; ++i) {
            float v = y[i];
            y[i] = v / (1.f + expf(-v));
        }
    }
    __syncthreads();
    if (t < 256) {
        float p = 0.f;
#pragma unroll
        for (int i = 0; i < 8; ++i) p += y[i] * y[i];
        atomicAdd(&ssq[t >> 4], p);
    }
    __syncthreads();
    if (t < 128) {
        float rn = rsqrtf(ssq[t >> 4] + EPSF) * 0.08838834764831845f;
        float ov[8];
#pragma unroll
        for (int i = 0; i < 8; ++i) ov[i] = y[i] * rn;
        *(uint4*)(qn + (size_t)s * 1024 + c8) = pack8(ov);
    } else if (t < 256) {
        float rn = rsqrtf(ssq[t >> 4] + EPSF);
        float ov[8];
#pragma unroll
        for (int i = 0; i < 8; ++i) ov[i] = y[i] * rn;
        *(uint4*)(kn + (size_t)s * 1024 + (c8 - 1024)) = pack8(ov);
    } else {
        int vh = (c8 - 2048) >> 7;
        float bb = beta[s * 16 + vh];
        float ov[8];
#pragma unroll
        for (int i = 0; i < 8; ++i) ov[i] = y[i] * bb;
        *(uint4*)(vb + (size_t)s * 2048 + (c8 - 2048)) = pack8(ov);
    }
}

// ------------- per-(chunk,head) precompute — emits MFMA-layout, pre-swizzled tiles -------------
// bufB per b (20480 u16): [ W[dv][c] 8192 | U(-u)[c][dk] swz 8192 | Aqk[i][j] swz 4096 ]
// bufK per bk=n*8+hs (16384 u16): [ qA[c][dk] swz 8192 | kA[dk][c] swz 8192 ]
// swizzle: 8-elem block index within row XOR'd with (row&7)  (bank-conflict-free frag reads)
__global__ __launch_bounds__(256) void precomp_kernel(const u16* __restrict__ qn,
                                                      const u16* __restrict__ kn,
                                                      const u16* __restrict__ vb,
                                                      const float* __restrict__ g,
                                                      const float* __restrict__ beta,
                                                      u16* __restrict__ bufB,
                                                      u16* __restrict__ bufK,
                                                      float* __restrict__ egc_arr,
                                                      float* __restrict__ ekd_arr,
                                                      float* __restrict__ eg) {
    const int b = blockIdx.x;  // n*16 + h
    const int n = b >> 4, h = b & 15, hs = h >> 1;
    const int t = threadIdx.x;
    const int s0 = n * 64;
    u16* BB = bufB + (size_t)b * 20480;

    __shared__ u16 sK[64 * 128];
    __shared__ u16 sVQ[64 * 128];
    __shared__ float Am[64 * 65];
    __shared__ float gc[64], bet[64], bexp[64];

#pragma unroll
    for (int i = 0; i < 4; ++i) {
        int flat = i * 256 + t;
        int c = flat >> 4, dc = (flat & 15) << 3;
        *(uint4*)(sK + c * 128 + dc)  = *(const uint4*)(kn + (size_t)(s0 + c) * 1024 + hs * 128 + dc);
        *(uint4*)(sVQ + c * 128 + dc) = *(const uint4*)(vb + (size_t)(s0 + c) * 2048 + h * 128 + dc);
    }
    if (t < 64) {
        gc[t] = g[(size_t)(s0 + t) * 16 + h];
        bet[t] = beta[(size_t)(s0 + t) * 16 + h];
    }
    __syncthreads();
    if (t == 0) {
        float run = 0.f;
        for (int c = 0; c < 64; ++c) { run += gc[c]; gc[c] = run; }
    }
    __syncthreads();
    if (t < 64) {
        float e = expf(gc[t]);
        float ek = expf(gc[63] - gc[t]);
        bexp[t] = bet[t] * e;
        egc_arr[b * 64 + t] = e;
        ekd_arr[b * 64 + t] = ek;
    }
    if (t == 0) eg[b] = expf(gc[63]);
    __syncthreads();

    // A[i][j] = -(k_beta_i . k_j) * exp(gc_i - gc_j), strictly lower
#pragma unroll 1
    for (int r = 0; r < 16; ++r) {
        int e = t + 256 * r;
        int i = e >> 6, j = e & 63;
        float val = 0.f;
        if (j < i) {
            float dot = 0.f;
            for (int d = 0; d < 128; d += 8) {
                float kf[8], kg[8];
                unpack8(*(const uint4*)(sK + i * 128 + d), kf);
                unpack8(*(const uint4*)(sK + j * 128 + d), kg);
#pragma unroll
                for (int q = 0; q < 8; ++q) dot = fmaf(kf[q], kg[q], dot);
            }
            val = -dot * bet[i] * expf(gc[i] - gc[j]);
        }
        Am[i * 65 + j] = val;
    }
    __syncthreads();

    // T = (I - A)^{-1} by forward substitution, in place
    if (t < 64) Am[t] = (t == 0) ? 1.f : 0.f;
    __syncthreads();
    for (int i = 1; i < 64; ++i) {
        float val = 0.f;
        if (t < 64) {
            for (int j = 0; j < i; ++j) val = fmaf(Am[i * 65 + j], Am[j * 65 + t], val);
            if (t == i) val += 1.f;
        }
        __syncthreads();
        if (t < 64) Am[i * 65 + t] = val;
        __syncthreads();
    }

    // u = T @ (k*beta*exp(gc)),  w = T @ v
    // store W as [dv][c] (linear), U as NEGATED, [c][dk], swizzled
    {
        const int c = t >> 2;
        const int dq = (t & 3) << 5;
        float accu[32], accw[32];
#pragma unroll
        for (int dd = 0; dd < 32; ++dd) { accu[dd] = 0.f; accw[dd] = 0.f; }
        for (int j = 0; j < 64; ++j) {
            float tc = Am[c * 65 + j];
            float tu = tc * bexp[j];
#pragma unroll
            for (int d8 = 0; d8 < 32; d8 += 8) {
                float kf[8], vf[8];
                unpack8(*(const uint4*)(sK + j * 128 + dq + d8), kf);
                unpack8(*(const uint4*)(sVQ + j * 128 + dq + d8), vf);
#pragma unroll
                for (int q = 0; q < 8; ++q) {
                    accu[d8 + q] = fmaf(tu, kf[q], accu[d8 + q]);
                    accw[d8 + q] = fmaf(tc, vf[q], accw[d8 + q]);
                }
            }
        }
        for (int dd = 0; dd < 32; ++dd)
            BB[(dq + dd) * 64 + c] = f2bf_rne(accw[dd]);
#pragma unroll
        for (int d8 = 0; d8 < 32; d8 += 8) {
            int base = 8192 + c * 128 + ((((dq + d8) >> 3) ^ (c & 7)) << 3);
#pragma unroll
            for (int qi = 0; qi < 4; ++qi) {
                u32 pr = (u32)f2bf_rne(-accu[d8 + 2 * qi]) | ((u32)f2bf_rne(-accu[d8 + 2 * qi + 1]) << 16);
                *(u32*)(BB + base + 2 * qi) = pr;
            }
        }
    }

    __syncthreads();  // done with sVQ as v-tile; reload as q-tile
#pragma unroll
    for (int i = 0; i < 4; ++i) {
        int flat = i * 256 + t;
        int c = flat >> 4, dc = (flat & 15) << 3;
        *(uint4*)(sVQ + c * 128 + dc) = *(const uint4*)(qn + (size_t)(s0 + c) * 1024 + hs * 128 + dc);
    }
    __syncthreads();

    // Aqk[i][j] = (q_i . k_j) * exp(gc_i - gc_j) for j<=i else 0 — row-major [i][j], swizzled
#pragma unroll 1
    for (int r = 0; r < 16; ++r) {
        int e = t + 256 * r;
        int j = e >> 6, i = e & 63;
        float val = 0.f;
        if (j <= i) {
            float dot = 0.f;
            for (int d = 0; d < 128; d += 8) {
                float qf[8], kf[8];
                unpack8(*(const uint4*)(sVQ + i * 128 + d), qf);
                unpack8(*(const uint4*)(sK + j * 128 + d), kf);
#pragma unroll
                for (int q = 0; q < 8; ++q) dot = fmaf(qf[q], kf[q], dot);
            }
            val = dot * expf(gc[i] - gc[j]);
        }
        BB[16384 + i * 64 + (((j >> 3) ^ (i & 7)) << 3) + (j & 7)] = f2bf_rne(val);
    }

    // qA[c][dk], kA[dk][c] per key head (h even writes)
    if ((h & 1) == 0) {
        u16* KB = bufK + (size_t)((n << 3) + hs) * 16384;
#pragma unroll 1
        for (int r = 0; r < 32; ++r) {
            int e = t + 256 * r;
            int dk = e >> 6, c = e & 63;
            KB[c * 128 + (((dk >> 3) ^ (c & 7)) << 3) + (dk & 7)] = sVQ[c * 128 + dk];
            KB[8192 + dk * 64 + (((c >> 3) ^ (dk & 7)) << 3) + (c & 7)] = sK[c * 128 + dk];
        }
    }
}

// ------------- MFMA sequential inter-chunk scan -------------
// 32 blocks = head(16) x dv-half(2); 4 waves; wave owns 16 dv cols.
// State S^T[dv][dk] fp32 in registers (8 frags), bf16 mirror STb in wave-private LDS.
#define STG 28928
#define OFF_AQK 8192
#define OFF_QA 12288
#define OFF_KA 20480
#define OFF_EGC 28672
#define OFF_EKD 28800

__global__ __launch_bounds__(256, 1) void scan_kernel(const u16* __restrict__ bufB,
                                                      const u16* __restrict__ bufK,
                                                      const float* __restrict__ egc_g,
                                                      const float* __restrict__ ekd_g,
                                                      const float* __restrict__ eg_g,
                                                      u16* __restrict__ o) {
    __shared__ __align__(16) u16 sStage[2 * STG];        // double-buffered staged tiles
    __shared__ __align__(16) u16 sSTb[4][16 * 136];      // wave-private bf16 state mirror [dv][dk]
    __shared__ __align__(16) u16 sVT[4][16 * 72];        // wave-private V^T [dv][c]
    __shared__ __align__(16) u16 sVTs[4][16 * 72];       // V^T * ekd[c]

    const int h = blockIdx.x >> 1;
    const int dvh = (blockIdx.x & 1) << 6;
    const int hs = h >> 1;
    const int w = threadIdx.x >> 6;
    const int l = threadIdx.x & 63;
    const int l15 = l & 15, l4 = l >> 4, l7 = l & 7;
    const int dv0 = dvh + (w << 4);

    u16* STb = sSTb[w];
    u16* VT  = sVT[w];
    u16* VTs = sVTs[w];

    for (int i = l; i < 16 * 136; i += 64) STb[i] = 0;

    f32x4 Sreg[8];
#pragma unroll
    for (int i = 0; i < 8; ++i) Sreg[i] = (f32x4){0.f, 0.f, 0.f, 0.f};

    auto stage = [&](int n2, u16* dst) {
        const int b2 = (n2 << 4) + h;
        const u16* sA = bufB + (size_t)b2 * 20480 + 8192 + (w * 3072 + l * 8);
        u16* dA = dst + w * 3072;
#pragma unroll
        for (int i = 0; i < 6; ++i) gload_lds16(sA + i * 512, dA + i * 512);
        const u16* sB = bufK + (size_t)((n2 << 3) + hs) * 16384 + (w * 4096 + l * 8);
        u16* dB = dst + 12288 + w * 4096;
#pragma unroll
        for (int i = 0; i < 8; ++i) gload_lds16(sB + i * 512, dB + i * 512);
        if (w == 0) gload_lds4(egc_g + (b2 << 6) + l, dst + OFF_EGC);
        else if (w == 1) gload_lds4(ekd_g + (b2 << 6) + l, dst + OFF_EKD);
    };
    auto loadW = [&](int n2, uint2 (&wr)[4]) {
        const u16* wb = bufB + (size_t)((n2 << 4) + h) * 20480 + (size_t)(dv0 + l15) * 64 + l4 * 4;
#pragma unroll
        for (int mt = 0; mt < 4; ++mt) wr[mt] = *(const uint2*)(wb + mt * 16);
    };

    uint2 wA[4], wB[4];
    float egA, egB;
    stage(0, sStage);
    loadW(0, wA);
    egA = eg_g[h];
    __syncthreads();

    int cur = 0;
    for (int n = 0; n < NCHUNK; ++n) {
        const u16* buf = sStage + cur * STG;
        if (n + 1 < NCHUNK) {
            stage(n + 1, sStage + (cur ^ 1) * STG);   // prefetch next chunk (in flight across barrier)
            loadW(n + 1, wB);
            egB = eg_g[((n + 1) << 4) + h];
        }
        const u16* bU = buf;
        const u16* bA = buf + OFF_AQK;
        const u16* bQ = buf + OFF_QA;
        const u16* bK = buf + OFF_KA;
        const float* egc = (const float*)(buf + OFF_EGC);
        const float* ekd = (const float*)(buf + OFF_EKD);

        // B-frags of old state (reused by comp1 and comp2a)
        s16x8 bF[4];
#pragma unroll
        for (int kk = 0; kk < 4; ++kk)
            bF[kk] = *(const s16x8*)(STb + l15 * 136 + kk * 32 + l4 * 8);

        // ---- comp1: V = W + (-U) @ S ----
        f32x4 V[4];
#pragma unroll
        for (int mt = 0; mt < 4; ++mt) {
            V[mt][0] = bfraw2f((u16)(wA[mt].x & 0xffffu));
            V[mt][1] = bfraw2f((u16)(wA[mt].x >> 16));
            V[mt][2] = bfraw2f((u16)(wA[mt].y & 0xffffu));
            V[mt][3] = bfraw2f((u16)(wA[mt].y >> 16));
        }
#pragma unroll
        for (int kk = 0; kk < 4; ++kk) {
            const int sw = ((kk * 4 + l4) ^ l7) << 3;
#pragma unroll
            for (int mt = 0; mt < 4; ++mt) {
                s16x8 a = *(const s16x8*)(bU + (mt * 16 + l15) * 128 + sw);
                V[mt] = __builtin_amdgcn_mfma_f32_16x16x32_bf16(a, bF[kk], V[mt], 0, 0, 0);
            }
        }

        // ---- comp2a: O = Q @ S_old, then scale rows by egc[c] ----
        f32x4 O[4];
#pragma unroll
        for (int mt = 0; mt < 4; ++mt) O[mt] = (f32x4){0.f, 0.f, 0.f, 0.f};
#pragma unroll
        for (int kk = 0; kk < 4; ++kk) {
            const int sw = ((kk * 4 + l4) ^ l7) << 3;
#pragma unroll
            for (int mt = 0; mt < 4; ++mt) {
                s16x8 a = *(const s16x8*)(bQ + (mt * 16 + l15) * 128 + sw);
                O[mt] = __builtin_amdgcn_mfma_f32_16x16x32_bf16(a, bF[kk], O[mt], 0, 0, 0);
            }
        }
#pragma unroll
        for (int mt = 0; mt < 4; ++mt)
#pragma unroll
            for (int r = 0; r < 4; ++r) O[mt][r] *= egc[mt * 16 + l4 * 4 + r];

        // ---- V -> VT (for Aqk@V) and VTs = V*ekd[c] (for state update) ----
#pragma unroll
        for (int mt = 0; mt < 4; ++mt) {
            const int cb = mt * 16 + l4 * 4;
            uint2 uv, us;
            uv.x = (u32)f2bf_rne(V[mt][0]) | ((u32)f2bf_rne(V[mt][1]) << 16);
            uv.y = (u32)f2bf_rne(V[mt][2]) | ((u32)f2bf_rne(V[mt][3]) << 16);
            us.x = (u32)f2bf_rne(V[mt][0] * ekd[cb]) | ((u32)f2bf_rne(V[mt][1] * ekd[cb + 1]) << 16);
            us.y = (u32)f2bf_rne(V[mt][2] * ekd[cb + 2]) | ((u32)f2bf_rne(V[mt][3] * ekd[cb + 3]) << 16);
            *(uint2*)(VT + l15 * 72 + cb) = uv;
            *(uint2*)(VTs + l15 * 72 + cb) = us;
        }

        // ---- comp2b: O += Aqk @ V ----
        s16x8 vF0 = *(const s16x8*)(VT + l15 * 72 + l4 * 8);
        s16x8 vF1 = *(const s16x8*)(VT + l15 * 72 + 32 + l4 * 8);
#pragma unroll
        for (int mt = 0; mt < 4; ++mt) {
            s16x8 a = *(const s16x8*)(bA + (mt * 16 + l15) * 64 + ((l4 ^ l7) << 3));
            O[mt] = __builtin_amdgcn_mfma_f32_16x16x32_bf16(a, vF0, O[mt], 0, 0, 0);
        }
#pragma unroll
        for (int mt = 0; mt < 4; ++mt) {
            s16x8 a = *(const s16x8*)(bA + (mt * 16 + l15) * 64 + (((4 + l4) ^ l7) << 3));
            O[mt] = __builtin_amdgcn_mfma_f32_16x16x32_bf16(a, vF1, O[mt], 0, 0, 0);
        }

        // ---- O store ----
        const int s0 = n << 6;
#pragma unroll
        for (int mt = 0; mt < 4; ++mt)
#pragma unroll
            for (int r = 0; r < 4; ++r)
                o[(size_t)(s0 + mt * 16 + l4 * 4 + r) * 2048 + (h << 7) + dv0 + l15] = f2bf_rne(O[mt][r]);

        // ---- comp3: S = eg*S + kA @ VTs  (C frag: row=dk, col=dv) ----
        s16x8 sF0 = *(const s16x8*)(VTs + l15 * 72 + l4 * 8);
        s16x8 sF1 = *(const s16x8*)(VTs + l15 * 72 + 32 + l4 * 8);
#pragma unroll
        for (int nt = 0; nt < 8; ++nt) {
#pragma unroll
            for (int r = 0; r < 4; ++r) Sreg[nt][r] *= egA;
            s16x8 a0 = *(const s16x8*)(bK + (nt * 16 + l15) * 64 + ((l4 ^ l7) << 3));
            Sreg[nt] = __builtin_amdgcn_mfma_f32_16x16x32_bf16(a0, sF0, Sreg[nt], 0, 0, 0);
            s16x8 a1 = *(const s16x8*)(bK + (nt * 16 + l15) * 64 + (((4 + l4) ^ l7) << 3));
            Sreg[nt] = __builtin_amdgcn_mfma_f32_16x16x32_bf16(a1, sF1, Sreg[nt], 0, 0, 0);
        }
        // bf16 mirror for next chunk's B-operands
#pragma unroll
        for (int nt = 0; nt < 8; ++nt) {
            uint2 sv;
            sv.x = (u32)f2bf_rne(Sreg[nt][0]) | ((u32)f2bf_rne(Sreg[nt][1]) << 16);
            sv.y = (u32)f2bf_rne(Sreg[nt][2]) | ((u32)f2bf_rne(Sreg[nt][3]) << 16);
            *(uint2*)(STb + l15 * 136 + nt * 16 + l4 * 4) = sv;
        }
        __syncthreads();   // drains stage vmcnt; protects shared stage buffers
#pragma unroll
        for (int i = 0; i < 4; ++i) wA[i] = wB[i];
        egA = egB;
        cur ^= 1;
    }
}

// ------------- gated rmsnorm * silu(z) -> bf16 -------------
__global__ __launch_bounds__(256) void gate_kernel(const u16* __restrict__ o,
                                                   const u16* __restrict__ Cz,
                                                   const float* __restrict__ norm_w,
                                                   u16* __restrict__ gated) {
    const int s = blockIdx.x, t = threadIdx.x;
    const int c8 = t << 3, hh = t >> 4;
    __shared__ float ssq[16];
    if (t < 16) ssq[t] = 0.f;
    float ov[8];
    unpack8(*(const uint4*)(o + (size_t)s * 2048 + c8), ov);
    float p = 0.f;
#pragma unroll
    for (int i = 0; i < 8; ++i) p += ov[i] * ov[i];
    __syncthreads();
    atomicAdd(&ssq[hh], p);
    __syncthreads();
    const float rms = rsqrtf(ssq[hh] * 0.0078125f + EPSF);
    float zf[8];
    unpack8(*(const uint4*)(Cz + (size_t)s * 2048 + c8), zf);
    const int d0 = c8 & 127;
    float res[8];
#pragma unroll
    for (int i = 0; i < 8; ++i) {
        float z = zf[i];
        float sz = z / (1.f + expf(-z));
        res[i] = ov[i] * rms * norm_w[d0 + i] * sz;
    }
    *(uint4*)(gated + (size_t)s * 2048 + c8) = pack8(res);
}

extern "C" void kernel_launch(void* const* d_in, const int* in_sizes, int n_in,
                              void* d_out, int out_size, void* d_ws, size_t ws_size,
                              hipStream_t stream) {
    (void)in_sizes; (void)n_in; (void)out_size; (void)ws_size;
    const float* x       = (const float*)d_in[0];
    const float* W_qkv   = (const float*)d_in[1];
    const float* W_z     = (const float*)d_in[2];
    const float* W_b     = (const float*)d_in[3];
    const float* W_a     = (const float*)d_in[4];
    const float* conv_w  = (const float*)d_in[5];
    const float* A_log   = (const float*)d_in[6];
    const float* dt_bias = (const float*)d_in[7];
    const float* norm_w  = (const float*)d_in[8];
    const float* W_out   = (const float*)d_in[9];

    // ---- static workspace layout: 186,654,720 B total (same footprint as baseline) ----
    char* p = (char*)d_ws;
    auto alloc = [&](size_t bytes) {
        char* r = p;
        p += (bytes + 255) & ~(size_t)255;
        return r;
    };
    u16* Cmix    = (u16*)alloc((size_t)S_LEN * NQKV * 2);       // 67.1 MB (dead after prep)
    char* extra  = alloc((size_t)50331648); (void)extra;        // 50.3 MB (bufB/bufK tail)
    u16* qn      = (u16*)alloc((size_t)S_LEN * HKN * DKD * 2);  // 16.8 MB
    u16* kn      = (u16*)alloc((size_t)S_LEN * HKN * DKD * 2);  // 16.8 MB
    u16* vb      = (u16*)alloc((size_t)S_LEN * HVN * DVD * 2);  // 33.5 MB
    float* egc   = (float*)alloc((size_t)NCHUNK * HVN * CLEN * 4);
    float* ekd   = (float*)alloc((size_t)NCHUNK * HVN * CLEN * 4);
    float* eg    = (float*)alloc((size_t)NCHUNK * HVN * 4);
    float* beta  = (float*)alloc((size_t)S_LEN * HVN * 4);
    float* g     = (float*)alloc((size_t)S_LEN * HVN * 4);
    // lifetime-disjoint overlays:
    u16* bufB  = Cmix;                                  // 2048 x 40960 B = 83.9 MB (over dead Cmix + extra)
    u16* bufK  = (u16*)((char*)Cmix + (size_t)83886080);// 1024 x 32768 B = 33.5 MB
    u16* o_buf = qn;                                    // 33.5 MB over qn+kn (scan reads neither)
    u16* Cz    = vb;                                    // z-GEMM after precomp read vb
    u16* gated = Cmix;                                  // gate after scan read bufB

    // 1) beta, g
    ba_kernel<<<S_LEN / 8, 256, 0, stream>>>(x, W_b, W_a, A_log, dt_bias, beta, g);
    // 2) mixed qkv GEMM
    gemm_kn<1, 0><<<dim3(NQKV / 128, S_LEN / 128), 256, 0, stream>>>(x, W_qkv, Cmix, S_LEN, NQKV, HID);
    // 3) conv + silu + l2norm prep
    prep_kernel<<<S_LEN, 512, 0, stream>>>(Cmix, conv_w, beta, qn, kn, vb);
    // 4) per-chunk precompute (writes MFMA-layout tiles over dead Cmix)
    precomp_kernel<<<NCHUNK * HVN, 256, 0, stream>>>(qn, kn, vb, g, beta, bufB, bufK, egc, ekd, eg);
    // 5) z GEMM (over dead vb)
    gemm_kn<1, 0><<<dim3(HID / 128, S_LEN / 128), 256, 0, stream>>>(x, W_z, Cz, S_LEN, HID, HID);
    // 6) MFMA sequential scan
    scan_kernel<<<HVN * 2, 256, 0, stream>>>(bufB, bufK, egc, ekd, eg, o_buf);
    // 7) gated rmsnorm (gated over dead bufB head)
    gate_kernel<<<S_LEN, 256, 0, stream>>>(o_buf, Cz, norm_w, gated);
    // 8) output projection -> fp32 d_out
    gemm_kn<0, 1><<<dim3(HID / 128, S_LEN / 128), 256, 0, stream>>>(gated, W_out, d_out, S_LEN, HID, HID);
}

// Round 2
// 1695.648 us; speedup vs baseline: 2.4822x; 1.5919x over previous
//
#include <hip/hip_runtime.h>

#define S_LEN 8192
#define HID 2048
#define HKN 8
#define HVN 16
#define DKD 128
#define DVD 128
#define NCHUNK 128
#define CLEN 64
#define NQKV 4096
#define EPSF 1e-6f

typedef unsigned int u32;
typedef unsigned short u16;
typedef __attribute__((ext_vector_type(8))) short s16x8;
typedef __attribute__((ext_vector_type(4))) float f32x4;

__device__ __forceinline__ float bfraw2f(u16 v) { return __uint_as_float(((u32)v) << 16); }
__device__ __forceinline__ u16 f2bf_rne(float f) {
    u32 u = __float_as_uint(f);
    u32 r = u + 0x7fffu + ((u >> 16) & 1u);
    return (u16)(r >> 16);
}
__device__ __forceinline__ void unpack8(uint4 u, float* f) {
    const u32 a[4] = {u.x, u.y, u.z, u.w};
#pragma unroll
    for (int q = 0; q < 4; ++q) {
        f[2*q]   = __uint_as_float(a[q] << 16);
        f[2*q+1] = __uint_as_float(a[q] & 0xffff0000u);
    }
}
__device__ __forceinline__ uint4 pack8(const float* v) {
    uint4 r;
    r.x = (u32)f2bf_rne(v[0]) | ((u32)f2bf_rne(v[1]) << 16);
    r.y = (u32)f2bf_rne(v[2]) | ((u32)f2bf_rne(v[3]) << 16);
    r.z = (u32)f2bf_rne(v[4]) | ((u32)f2bf_rne(v[5]) << 16);
    r.w = (u32)f2bf_rne(v[6]) | ((u32)f2bf_rne(v[7]) << 16);
    return r;
}

// async global->LDS staging (lane-strided 16B; LDS dest wave-uniform base + lane*16)
__device__ __forceinline__ void gload_lds16(const u16* g, u16* l) {
    __builtin_amdgcn_global_load_lds((const __attribute__((address_space(1))) unsigned int*)g,
                                     (__attribute__((address_space(3))) unsigned int*)l, 16, 0, 0);
}
__device__ __forceinline__ void gload_lds4(const float* g, u16* l) {
    __builtin_amdgcn_global_load_lds((const __attribute__((address_space(1))) unsigned int*)g,
                                     (__attribute__((address_space(3))) unsigned int*)l, 4, 0, 0);
}

// ------------- b,a projections (scalar, broadcast-x) + activations -------------
__global__ __launch_bounds__(256) void ba_kernel(const float* __restrict__ x,
                                                 const float* __restrict__ Wb,
                                                 const float* __restrict__ Wa,
                                                 const float* __restrict__ A_log,
                                                 const float* __restrict__ dt_bias,
                                                 float* __restrict__ beta,
                                                 float* __restrict__ g) {
    const int t = threadIdx.x;
    const int row = blockIdx.x * 8 + (t >> 5);
    const int c = t & 31;
    const int cc = c & 15;
    const float* W = (c < 16) ? Wb : Wa;
    const float* xr = x + (size_t)row * HID;
    float acc = 0.f;
    for (int k = 0; k < HID; ++k) acc = fmaf(xr[k], W[k * 16 + cc], acc);
    if (c < 16) {
        beta[row * 16 + cc] = 1.f / (1.f + expf(-acc));
    } else {
        float v = acc + dt_bias[cc];
        float sp = (v > 20.f) ? v : log1pf(expf(v));
        g[row * 16 + cc] = -expf(A_log[cc]) * sp;
    }
}

// ------------- fp32 -> bf16 bulk convert -------------
__global__ __launch_bounds__(256) void cvt_x_kernel(const float* __restrict__ x,
                                                    u16* __restrict__ xb) {
    const size_t i8 = ((size_t)blockIdx.x * 256 + threadIdx.x) << 3;
    float4 a = *(const float4*)(x + i8);
    float4 b = *(const float4*)(x + i8 + 4);
    float v[8] = {a.x, a.y, a.z, a.w, b.x, b.y, b.z, b.w};
    *(uint4*)(xb + i8) = pack8(v);
}

// ------------- W [K,N] fp32 -> Wt [N,K] bf16 (tiled transpose) -------------
__global__ __launch_bounds__(256) void cvt_wT_kernel(const float* __restrict__ W,
                                                     u16* __restrict__ Wt,
                                                     int N, int K) {
    __shared__ u16 T[64 * 72];
    const int t = threadIdx.x;
    const int n0 = blockIdx.x * 64;
    const int k0 = blockIdx.y * 64;
#pragma unroll
    for (int i = 0; i < 4; ++i) {
        int flat = i * 256 + t;
        int kr = flat >> 4, c4 = (flat & 15) << 2;  // 64 k-rows x 16 n-quads
        float4 v = *(const float4*)(W + (size_t)(k0 + kr) * N + n0 + c4);
        T[(c4 + 0) * 72 + kr] = f2bf_rne(v.x);
        T[(c4 + 1) * 72 + kr] = f2bf_rne(v.y);
        T[(c4 + 2) * 72 + kr] = f2bf_rne(v.z);
        T[(c4 + 3) * 72 + kr] = f2bf_rne(v.w);
    }
    __syncthreads();
#pragma unroll
    for (int i = 0; i < 2; ++i) {
        int flat = i * 256 + t;
        int n = flat >> 3, k8 = (flat & 7) << 3;    // 64 n-rows x 8 k-octs
        *(uint4*)(Wt + (size_t)(n0 + n) * K + k0 + k8) = *(const uint4*)(T + n * 72 + k8);
    }
}

// ------------- MFMA GEMM (m97 structure): C[M,N] = A[M,K] * Bt[N,K]^T, both bf16 -------------
// global_load_lds staging for both operands into linear LDS; 128x128 tile, BK=64.
template <int F32OUT>
__global__ __launch_bounds__(256) void gemm_bt(const u16* __restrict__ A,
                                               const u16* __restrict__ Bt,
                                               void* __restrict__ Cv,
                                               int M, int N, int K) {
    __shared__ __align__(16) u16 As[128 * 64];
    __shared__ __align__(16) u16 Bs[128 * 64];
    const int t = threadIdx.x;
    const int n0 = blockIdx.x * 128;
    const int m0 = blockIdx.y * 128;
    const int w = t >> 6, lane = t & 63;
    const int wm = (w >> 1) * 64, wn = (w & 1) * 64;
    const int ml = lane & 15, kq = lane >> 4;
    f32x4 acc[4][4];
#pragma unroll
    for (int i = 0; i < 4; ++i)
#pragma unroll
        for (int j = 0; j < 4; ++j) acc[i][j] = (f32x4){0.f, 0.f, 0.f, 0.f};

    for (int k0 = 0; k0 < K; k0 += 64) {
#pragma unroll
        for (int r = 0; r < 4; ++r) {
            int flat = r * 256 + t;
            int row = flat >> 3, kc = (flat & 7) << 3;
            gload_lds16(A  + (size_t)(m0 + row) * K + k0 + kc, As + flat * 8);
            gload_lds16(Bt + (size_t)(n0 + row) * K + k0 + kc, Bs + flat * 8);
        }
        __syncthreads();
#pragma unroll
        for (int ks = 0; ks < 2; ++ks) {
            s16x8 af[4], bfr[4];
#pragma unroll
            for (int mt = 0; mt < 4; ++mt)
                af[mt] = *(const s16x8*)(As + (wm + mt * 16 + ml) * 64 + ks * 32 + kq * 8);
#pragma unroll
            for (int nt = 0; nt < 4; ++nt)
                bfr[nt] = *(const s16x8*)(Bs + (wn + nt * 16 + ml) * 64 + ks * 32 + kq * 8);
#pragma unroll
            for (int mt = 0; mt < 4; ++mt)
#pragma unroll
                for (int nt = 0; nt < 4; ++nt)
                    acc[mt][nt] = __builtin_amdgcn_mfma_f32_16x16x32_bf16(af[mt], bfr[nt], acc[mt][nt], 0, 0, 0);
        }
        __syncthreads();
    }
#pragma unroll
    for (int mt = 0; mt < 4; ++mt)
#pragma unroll
        for (int nt = 0; nt < 4; ++nt)
#pragma unroll
            for (int r = 0; r < 4; ++r) {
                int row = m0 + wm + mt * 16 + kq * 4 + r;
                int col = n0 + wn + nt * 16 + ml;
                float v = acc[mt][nt][r];
                if (F32OUT)
                    ((float*)Cv)[(size_t)row * N + col] = v;
                else
                    ((u16*)Cv)[(size_t)row * N + col] = f2bf_rne(v);
            }
}

// ------------- conv(K=4) + silu + l2norm + beta-fold prep -------------
__global__ __launch_bounds__(512) void prep_kernel(const u16* __restrict__ Cmix,
                                                   const float* __restrict__ conv_w,
                                                   const float* __restrict__ beta,
                                                   u16* __restrict__ qn,
                                                   u16* __restrict__ kn,
                                                   u16* __restrict__ vb) {
    const int s = blockIdx.x;
    const int t = threadIdx.x;
    const int c8 = t << 3;
    __shared__ float ssq[16];
    if (t < 16) ssq[t] = 0.f;

    float y[8];
#pragma unroll
    for (int i = 0; i < 8; ++i) y[i] = 0.f;
    {
        uint4 mrow[4];
#pragma unroll
        for (int j = 0; j < 4; ++j) {
            int r = s - 3 + j;
            if (r >= 0) mrow[j] = *(const uint4*)(Cmix + (size_t)r * NQKV + c8);
            else        mrow[j] = uint4{0u, 0u, 0u, 0u};
        }
        float cw[8][4];
#pragma unroll
        for (int i = 0; i < 8; ++i) {
            float4 cv = *(const float4*)(conv_w + (size_t)(c8 + i) * 4);
            cw[i][0] = cv.x; cw[i][1] = cv.y; cw[i][2] = cv.z; cw[i][3] = cv.w;
        }
#pragma unroll
        for (int j = 0; j < 4; ++j) {
            float mf[8];
            unpack8(mrow[j], mf);
#pragma unroll
            for (int i = 0; i < 8; ++i) y[i] = fmaf(mf[i], cw[i][j], y[i]);
        }
#pragma unroll
        for (int i = 0; i < 8; ++i) {
            float v = y[i];
            y[i] = v / (1.f + expf(-v));
        }
    }
    __syncthreads();
    if (t < 256) {
        float p = 0.f;
#pragma unroll
        for (int i = 0; i < 8; ++i) p += y[i] * y[i];
        atomicAdd(&ssq[t >> 4], p);
    }
    __syncthreads();
    if (t < 128) {
        float rn = rsqrtf(ssq[t >> 4] + EPSF) * 0.08838834764831845f;
        float ov[8];
#pragma unroll
        for (int i = 0; i < 8; ++i) ov[i] = y[i] * rn;
        *(uint4*)(qn + (size_t)s * 1024 + c8) = pack8(ov);
    } else if (t < 256) {
        float rn = rsqrtf(ssq[t >> 4] + EPSF);
        float ov[8];
#pragma unroll
        for (int i = 0; i < 8; ++i) ov[i] = y[i] * rn;
        *(uint4*)(kn + (size_t)s * 1024 + (c8 - 1024)) = pack8(ov);
    } else {
        int vh = (c8 - 2048) >> 7;
        float bb = beta[s * 16 + vh];
        float ov[8];
#pragma unroll
        for (int i = 0; i < 8; ++i) ov[i] = y[i] * bb;
        *(uint4*)(vb + (size_t)s * 2048 + (c8 - 2048)) = pack8(ov);
    }
}

// ------------- per-(chunk,head) precompute — emits MFMA-layout, pre-swizzled tiles -------------
// bufB per b (20480 u16): [ W[dv][c] 8192 | U(-u)[c][dk] swz 8192 | Aqk[i][j] swz 4096 ]
// bufK per bk=n*8+hs (16384 u16): [ qA[c][dk] swz 8192 | kA[dk][c] swz 8192 ]
// swizzle: 8-elem block index within row XOR'd with (row&7)  (bank-conflict-free frag reads)
__global__ __launch_bounds__(256) void precomp_kernel(const u16* __restrict__ qn,
                                                      const u16* __restrict__ kn,
                                                      const u16* __restrict__ vb,
                                                      const float* __restrict__ g,
                                                      const float* __restrict__ beta,
                                                      u16* __restrict__ bufB,
                                                      u16* __restrict__ bufK,
                                                      float* __restrict__ egc_arr,
                                                      float* __restrict__ ekd_arr,
                                                      float* __restrict__ eg) {
    const int b = blockIdx.x;  // n*16 + h
    const int n = b >> 4, h = b & 15, hs = h >> 1;
    const int t = threadIdx.x;
    const int s0 = n * 64;
    u16* BB = bufB + (size_t)b * 20480;

    __shared__ u16 sK[64 * 128];
    __shared__ u16 sVQ[64 * 128];
    __shared__ float Am[64 * 65];
    __shared__ float gc[64], bet[64], bexp[64];

#pragma unroll
    for (int i = 0; i < 4; ++i) {
        int flat = i * 256 + t;
        int c = flat >> 4, dc = (flat & 15) << 3;
        *(uint4*)(sK + c * 128 + dc)  = *(const uint4*)(kn + (size_t)(s0 + c) * 1024 + hs * 128 + dc);
        *(uint4*)(sVQ + c * 128 + dc) = *(const uint4*)(vb + (size_t)(s0 + c) * 2048 + h * 128 + dc);
    }
    if (t < 64) {
        gc[t] = g[(size_t)(s0 + t) * 16 + h];
        bet[t] = beta[(size_t)(s0 + t) * 16 + h];
    }
    __syncthreads();
    if (t == 0) {
        float run = 0.f;
        for (int c = 0; c < 64; ++c) { run += gc[c]; gc[c] = run; }
    }
    __syncthreads();
    if (t < 64) {
        float e = expf(gc[t]);
        float ek = expf(gc[63] - gc[t]);
        bexp[t] = bet[t] * e;
        egc_arr[b * 64 + t] = e;
        ekd_arr[b * 64 + t] = ek;
    }
    if (t == 0) eg[b] = expf(gc[63]);
    __syncthreads();

    // A[i][j] = -(k_beta_i . k_j) * exp(gc_i - gc_j), strictly lower
#pragma unroll 1
    for (int r = 0; r < 16; ++r) {
        int e = t + 256 * r;
        int i = e >> 6, j = e & 63;
        float val = 0.f;
        if (j < i) {
            float dot = 0.f;
            for (int d = 0; d < 128; d += 8) {
                float kf[8], kg[8];
                unpack8(*(const uint4*)(sK + i * 128 + d), kf);
                unpack8(*(const uint4*)(sK + j * 128 + d), kg);
#pragma unroll
                for (int q = 0; q < 8; ++q) dot = fmaf(kf[q], kg[q], dot);
            }
            val = -dot * bet[i] * expf(gc[i] - gc[j]);
        }
        Am[i * 65 + j] = val;
    }
    __syncthreads();

    // T = (I - A)^{-1} by forward substitution, in place
    if (t < 64) Am[t] = (t == 0) ? 1.f : 0.f;
    __syncthreads();
    for (int i = 1; i < 64; ++i) {
        float val = 0.f;
        if (t < 64) {
            for (int j = 0; j < i; ++j) val = fmaf(Am[i * 65 + j], Am[j * 65 + t], val);
            if (t == i) val += 1.f;
        }
        __syncthreads();
        if (t < 64) Am[i * 65 + t] = val;
        __syncthreads();
    }

    // u = T @ (k*beta*exp(gc)),  w = T @ v
    // store W as [dv][c] (linear), U as NEGATED, [c][dk], swizzled
    {
        const int c = t >> 2;
        const int dq = (t & 3) << 5;
        float accu[32], accw[32];
#pragma unroll
        for (int dd = 0; dd < 32; ++dd) { accu[dd] = 0.f; accw[dd] = 0.f; }
        for (int j = 0; j < 64; ++j) {
            float tc = Am[c * 65 + j];
            float tu = tc * bexp[j];
#pragma unroll
            for (int d8 = 0; d8 < 32; d8 += 8) {
                float kf[8], vf[8];
                unpack8(*(const uint4*)(sK + j * 128 + dq + d8), kf);
                unpack8(*(const uint4*)(sVQ + j * 128 + dq + d8), vf);
#pragma unroll
                for (int q = 0; q < 8; ++q) {
                    accu[d8 + q] = fmaf(tu, kf[q], accu[d8 + q]);
                    accw[d8 + q] = fmaf(tc, vf[q], accw[d8 + q]);
                }
            }
        }
        for (int dd = 0; dd < 32; ++dd)
            BB[(dq + dd) * 64 + c] = f2bf_rne(accw[dd]);
#pragma unroll
        for (int d8 = 0; d8 < 32; d8 += 8) {
            int base = 8192 + c * 128 + ((((dq + d8) >> 3) ^ (c & 7)) << 3);
#pragma unroll
            for (int qi = 0; qi < 4; ++qi) {
                u32 pr = (u32)f2bf_rne(-accu[d8 + 2 * qi]) | ((u32)f2bf_rne(-accu[d8 + 2 * qi + 1]) << 16);
                *(u32*)(BB + base + 2 * qi) = pr;
            }
        }
    }

    __syncthreads();  // done with sVQ as v-tile; reload as q-tile
#pragma unroll
    for (int i = 0; i < 4; ++i) {
        int flat = i * 256 + t;
        int c = flat >> 4, dc = (flat & 15) << 3;
        *(uint4*)(sVQ + c * 128 + dc) = *(const uint4*)(qn + (size_t)(s0 + c) * 1024 + hs * 128 + dc);
    }
    __syncthreads();

    // Aqk[i][j] = (q_i . k_j) * exp(gc_i - gc_j) for j<=i else 0 — row-major [i][j], swizzled
#pragma unroll 1
    for (int r = 0; r < 16; ++r) {
        int e = t + 256 * r;
        int j = e >> 6, i = e & 63;
        float val = 0.f;
        if (j <= i) {
            float dot = 0.f;
            for (int d = 0; d < 128; d += 8) {
                float qf[8], kf[8];
                unpack8(*(const uint4*)(sVQ + i * 128 + d), qf);
                unpack8(*(const uint4*)(sK + j * 128 + d), kf);
#pragma unroll
                for (int q = 0; q < 8; ++q) dot = fmaf(qf[q], kf[q], dot);
            }
            val = dot * expf(gc[i] - gc[j]);
        }
        BB[16384 + i * 64 + (((j >> 3) ^ (i & 7)) << 3) + (j & 7)] = f2bf_rne(val);
    }

    // qA[c][dk], kA[dk][c] per key head (h even writes)
    if ((h & 1) == 0) {
        u16* KB = bufK + (size_t)((n << 3) + hs) * 16384;
#pragma unroll 1
        for (int r = 0; r < 32; ++r) {
            int e = t + 256 * r;
            int dk = e >> 6, c = e & 63;
            KB[c * 128 + (((dk >> 3) ^ (c & 7)) << 3) + (dk & 7)] = sVQ[c * 128 + dk];
            KB[8192 + dk * 64 + (((c >> 3) ^ (dk & 7)) << 3) + (c & 7)] = sK[c * 128 + dk];
        }
    }
}

// ------------- MFMA sequential inter-chunk scan -------------
// 32 blocks = head(16) x dv-half(2); 4 waves; wave owns 16 dv cols.
// State S^T[dv][dk] fp32 in registers (8 frags), bf16 mirror STb in wave-private LDS.
#define STG 28928
#define OFF_AQK 8192
#define OFF_QA 12288
#define OFF_KA 20480
#define OFF_EGC 28672
#define OFF_EKD 28800

__global__ __launch_bounds__(256, 1) void scan_kernel(const u16* __restrict__ bufB,
                                                      const u16* __restrict__ bufK,
                                                      const float* __restrict__ egc_g,
                                                      const float* __restrict__ ekd_g,
                                                      const float* __restrict__ eg_g,
                                                      u16* __restrict__ o) {
    __shared__ __align__(16) u16 sStage[2 * STG];        // double-buffered staged tiles
    __shared__ __align__(16) u16 sSTb[4][16 * 136];      // wave-private bf16 state mirror [dv][dk]
    __shared__ __align__(16) u16 sVT[4][16 * 72];        // wave-private V^T [dv][c]
    __shared__ __align__(16) u16 sVTs[4][16 * 72];       // V^T * ekd[c]

    const int h = blockIdx.x >> 1;
    const int dvh = (blockIdx.x & 1) << 6;
    const int hs = h >> 1;
    const int w = threadIdx.x >> 6;
    const int l = threadIdx.x & 63;
    const int l15 = l & 15, l4 = l >> 4, l7 = l & 7;
    const int dv0 = dvh + (w << 4);

    u16* STb = sSTb[w];
    u16* VT  = sVT[w];
    u16* VTs = sVTs[w];

    for (int i = l; i < 16 * 136; i += 64) STb[i] = 0;

    f32x4 Sreg[8];
#pragma unroll
    for (int i = 0; i < 8; ++i) Sreg[i] = (f32x4){0.f, 0.f, 0.f, 0.f};

    auto stage = [&](int n2, u16* dst) {
        const int b2 = (n2 << 4) + h;
        const u16* sA = bufB + (size_t)b2 * 20480 + 8192 + (w * 3072 + l * 8);
        u16* dA = dst + w * 3072;
#pragma unroll
        for (int i = 0; i < 6; ++i) gload_lds16(sA + i * 512, dA + i * 512);
        const u16* sB = bufK + (size_t)((n2 << 3) + hs) * 16384 + (w * 4096 + l * 8);
        u16* dB = dst + 12288 + w * 4096;
#pragma unroll
        for (int i = 0; i < 8; ++i) gload_lds16(sB + i * 512, dB + i * 512);
        if (w == 0) gload_lds4(egc_g + (b2 << 6) + l, dst + OFF_EGC);
        else if (w == 1) gload_lds4(ekd_g + (b2 << 6) + l, dst + OFF_EKD);
    };
    auto loadW = [&](int n2, uint2 (&wr)[4]) {
        const u16* wb = bufB + (size_t)((n2 << 4) + h) * 20480 + (size_t)(dv0 + l15) * 64 + l4 * 4;
#pragma unroll
        for (int mt = 0; mt < 4; ++mt) wr[mt] = *(const uint2*)(wb + mt * 16);
    };

    uint2 wA[4], wB[4];
    float egA, egB;
    stage(0, sStage);
    loadW(0, wA);
    egA = eg_g[h];
    __syncthreads();

    int cur = 0;
    for (int n = 0; n < NCHUNK; ++n) {
        const u16* buf = sStage + cur * STG;
        if (n + 1 < NCHUNK) {
            stage(n + 1, sStage + (cur ^ 1) * STG);   // prefetch next chunk (in flight across barrier)
            loadW(n + 1, wB);
            egB = eg_g[((n + 1) << 4) + h];
        }
        const u16* bU = buf;
        const u16* bA = buf + OFF_AQK;
        const u16* bQ = buf + OFF_QA;
        const u16* bK = buf + OFF_KA;
        const float* egc = (const float*)(buf + OFF_EGC);
        const float* ekd = (const float*)(buf + OFF_EKD);

        // B-frags of old state (reused by comp1 and comp2a)
        s16x8 bF[4];
#pragma unroll
        for (int kk = 0; kk < 4; ++kk)
            bF[kk] = *(const s16x8*)(STb + l15 * 136 + kk * 32 + l4 * 8);

        // ---- comp1: V = W + (-U) @ S ----
        f32x4 V[4];
#pragma unroll
        for (int mt = 0; mt < 4; ++mt) {
            V[mt][0] = bfraw2f((u16)(wA[mt].x & 0xffffu));
            V[mt][1] = bfraw2f((u16)(wA[mt].x >> 16));
            V[mt][2] = bfraw2f((u16)(wA[mt].y & 0xffffu));
            V[mt][3] = bfraw2f((u16)(wA[mt].y >> 16));
        }
#pragma unroll
        for (int kk = 0; kk < 4; ++kk) {
            const int sw = ((kk * 4 + l4) ^ l7) << 3;
#pragma unroll
            for (int mt = 0; mt < 4; ++mt) {
                s16x8 a = *(const s16x8*)(bU + (mt * 16 + l15) * 128 + sw);
                V[mt] = __builtin_amdgcn_mfma_f32_16x16x32_bf16(a, bF[kk], V[mt], 0, 0, 0);
            }
        }

        // ---- comp2a: O = Q @ S_old, then scale rows by egc[c] ----
        f32x4 O[4];
#pragma unroll
        for (int mt = 0; mt < 4; ++mt) O[mt] = (f32x4){0.f, 0.f, 0.f, 0.f};
#pragma unroll
        for (int kk = 0; kk < 4; ++kk) {
            const int sw = ((kk * 4 + l4) ^ l7) << 3;
#pragma unroll
            for (int mt = 0; mt < 4; ++mt) {
                s16x8 a = *(const s16x8*)(bQ + (mt * 16 + l15) * 128 + sw);
                O[mt] = __builtin_amdgcn_mfma_f32_16x16x32_bf16(a, bF[kk], O[mt], 0, 0, 0);
            }
        }
#pragma unroll
        for (int mt = 0; mt < 4; ++mt)
#pragma unroll
            for (int r = 0; r < 4; ++r) O[mt][r] *= egc[mt * 16 + l4 * 4 + r];

        // ---- V -> VT (for Aqk@V) and VTs = V*ekd[c] (for state update) ----
#pragma unroll
        for (int mt = 0; mt < 4; ++mt) {
            const int cb = mt * 16 + l4 * 4;
            uint2 uv, us;
            uv.x = (u32)f2bf_rne(V[mt][0]) | ((u32)f2bf_rne(V[mt][1]) << 16);
            uv.y = (u32)f2bf_rne(V[mt][2]) | ((u32)f2bf_rne(V[mt][3]) << 16);
            us.x = (u32)f2bf_rne(V[mt][0] * ekd[cb]) | ((u32)f2bf_rne(V[mt][1] * ekd[cb + 1]) << 16);
            us.y = (u32)f2bf_rne(V[mt][2] * ekd[cb + 2]) | ((u32)f2bf_rne(V[mt][3] * ekd[cb + 3]) << 16);
            *(uint2*)(VT + l15 * 72 + cb) = uv;
            *(uint2*)(VTs + l15 * 72 + cb) = us;
        }

        // ---- comp2b: O += Aqk @ V ----
        s16x8 vF0 = *(const s16x8*)(VT + l15 * 72 + l4 * 8);
        s16x8 vF1 = *(const s16x8*)(VT + l15 * 72 + 32 + l4 * 8);
#pragma unroll
        for (int mt = 0; mt < 4; ++mt) {
            s16x8 a = *(const s16x8*)(bA + (mt * 16 + l15) * 64 + ((l4 ^ l7) << 3));
            O[mt] = __builtin_amdgcn_mfma_f32_16x16x32_bf16(a, vF0, O[mt], 0, 0, 0);
        }
#pragma unroll
        for (int mt = 0; mt < 4; ++mt) {
            s16x8 a = *(const s16x8*)(bA + (mt * 16 + l15) * 64 + (((4 + l4) ^ l7) << 3));
            O[mt] = __builtin_amdgcn_mfma_f32_16x16x32_bf16(a, vF1, O[mt], 0, 0, 0);
        }

        // ---- O store ----
        const int s0 = n << 6;
#pragma unroll
        for (int mt = 0; mt < 4; ++mt)
#pragma unroll
            for (int r = 0; r < 4; ++r)
                o[(size_t)(s0 + mt * 16 + l4 * 4 + r) * 2048 + (h << 7) + dv0 + l15] = f2bf_rne(O[mt][r]);

        // ---- comp3: S = eg*S + kA @ VTs  (C frag: row=dk, col=dv) ----
        s16x8 sF0 = *(const s16x8*)(VTs + l15 * 72 + l4 * 8);
        s16x8 sF1 = *(const s16x8*)(VTs + l15 * 72 + 32 + l4 * 8);
#pragma unroll
        for (int nt = 0; nt < 8; ++nt) {
#pragma unroll
            for (int r = 0; r < 4; ++r) Sreg[nt][r] *= egA;
            s16x8 a0 = *(const s16x8*)(bK + (nt * 16 + l15) * 64 + ((l4 ^ l7) << 3));
            Sreg[nt] = __builtin_amdgcn_mfma_f32_16x16x32_bf16(a0, sF0, Sreg[nt], 0, 0, 0);
            s16x8 a1 = *(const s16x8*)(bK + (nt * 16 + l15) * 64 + (((4 + l4) ^ l7) << 3));
            Sreg[nt] = __builtin_amdgcn_mfma_f32_16x16x32_bf16(a1, sF1, Sreg[nt], 0, 0, 0);
        }
        // bf16 mirror for next chunk's B-operands
#pragma unroll
        for (int nt = 0; nt < 8; ++nt) {
            uint2 sv;
            sv.x = (u32)f2bf_rne(Sreg[nt][0]) | ((u32)f2bf_rne(Sreg[nt][1]) << 16);
            sv.y = (u32)f2bf_rne(Sreg[nt][2]) | ((u32)f2bf_rne(Sreg[nt][3]) << 16);
            *(uint2*)(STb + l15 * 136 + nt * 16 + l4 * 4) = sv;
        }
        __syncthreads();   // drains stage vmcnt; protects shared stage buffers
#pragma unroll
        for (int i = 0; i < 4; ++i) wA[i] = wB[i];
        egA = egB;
        cur ^= 1;
    }
}

// ------------- gated rmsnorm * silu(z) -> bf16 -------------
__global__ __launch_bounds__(256) void gate_kernel(const u16* __restrict__ o,
                                                   const u16* __restrict__ Cz,
                                                   const float* __restrict__ norm_w,
                                                   u16* __restrict__ gated) {
    const int s = blockIdx.x, t = threadIdx.x;
    const int c8 = t << 3, hh = t >> 4;
    __shared__ float ssq[16];
    if (t < 16) ssq[t] = 0.f;
    float ov[8];
    unpack8(*(const uint4*)(o + (size_t)s * 2048 + c8), ov);
    float p = 0.f;
#pragma unroll
    for (int i = 0; i < 8; ++i) p += ov[i] * ov[i];
    __syncthreads();
    atomicAdd(&ssq[hh], p);
    __syncthreads();
    const float rms = rsqrtf(ssq[hh] * 0.0078125f + EPSF);
    float zf[8];
    unpack8(*(const uint4*)(Cz + (size_t)s * 2048 + c8), zf);
    const int d0 = c8 & 127;
    float res[8];
#pragma unroll
    for (int i = 0; i < 8; ++i) {
        float z = zf[i];
        float sz = z / (1.f + expf(-z));
        res[i] = ov[i] * rms * norm_w[d0 + i] * sz;
    }
    *(uint4*)(gated + (size_t)s * 2048 + c8) = pack8(res);
}

extern "C" void kernel_launch(void* const* d_in, const int* in_sizes, int n_in,
                              void* d_out, int out_size, void* d_ws, size_t ws_size,
                              hipStream_t stream) {
    (void)in_sizes; (void)n_in; (void)out_size; (void)ws_size;
    const float* x       = (const float*)d_in[0];
    const float* W_qkv   = (const float*)d_in[1];
    const float* W_z     = (const float*)d_in[2];
    const float* W_b     = (const float*)d_in[3];
    const float* W_a     = (const float*)d_in[4];
    const float* conv_w  = (const float*)d_in[5];
    const float* A_log   = (const float*)d_in[6];
    const float* dt_bias = (const float*)d_in[7];
    const float* norm_w  = (const float*)d_in[8];
    const float* W_out   = (const float*)d_in[9];

    // ---- static workspace layout: 186,654,720 B total (same footprint as baseline) ----
    char* p = (char*)d_ws;
    auto alloc = [&](size_t bytes) {
        char* r = p;
        p += (bytes + 255) & ~(size_t)255;
        return r;
    };
    u16* Cmix    = (u16*)alloc((size_t)S_LEN * NQKV * 2);       // 67.1 MB (dead after prep)
    char* extra  = alloc((size_t)50331648); (void)extra;        // 50.3 MB (bufB/bufK tail)
    u16* qn      = (u16*)alloc((size_t)S_LEN * HKN * DKD * 2);  // 16.8 MB
    u16* kn      = (u16*)alloc((size_t)S_LEN * HKN * DKD * 2);  // 16.8 MB
    u16* vb      = (u16*)alloc((size_t)S_LEN * HVN * DVD * 2);  // 33.5 MB
    float* egc   = (float*)alloc((size_t)NCHUNK * HVN * CLEN * 4);
    float* ekd   = (float*)alloc((size_t)NCHUNK * HVN * CLEN * 4);
    float* eg    = (float*)alloc((size_t)NCHUNK * HVN * 4);
    float* beta  = (float*)alloc((size_t)S_LEN * HVN * 4);
    float* g     = (float*)alloc((size_t)S_LEN * HVN * 4);
    // lifetime-disjoint overlays:
    u16* bufB  = Cmix;                                  // 2048 x 40960 B = 83.9 MB (over dead Cmix + extra)
    u16* bufK  = (u16*)((char*)Cmix + (size_t)83886080);// 1024 x 32768 B = 33.5 MB
    u16* o_buf = qn;                                    // 33.5 MB over qn+kn (scan reads neither)
    u16* Cz    = vb;                                    // z-GEMM after precomp read vb
    u16* gated = Cmix;                                  // gate after scan read bufB
    // bf16 operand scratch inside d_out (all dead before final GEMM writes d_out):
    u16* xbf    = (u16*)d_out;                          // [0, 33.5M)  x as bf16
    u16* Wq_t   = (u16*)d_out + (size_t)16777216;       // [33.5M, 50.3M)  W_qkv^T bf16 [4096,2048]
    u16* Wz_t   = (u16*)d_out + (size_t)25165824;       // [50.3M, 58.7M)  W_z^T   bf16 [2048,2048]
    u16* Wout_t = qn;                                   // after gate consumed o_buf: W_out^T bf16

    // 1) beta, g
    ba_kernel<<<S_LEN / 8, 256, 0, stream>>>(x, W_b, W_a, A_log, dt_bias, beta, g);
    // 2) operand conversions (one-time, memory-bound)
    cvt_x_kernel<<<S_LEN * HID / (256 * 8), 256, 0, stream>>>(x, xbf);
    cvt_wT_kernel<<<dim3(NQKV / 64, HID / 64), 256, 0, stream>>>(W_qkv, Wq_t, NQKV, HID);
    cvt_wT_kernel<<<dim3(HID / 64, HID / 64), 256, 0, stream>>>(W_z, Wz_t, HID, HID);
    // 3) mixed qkv GEMM (bf16 x bf16^T, global_load_lds staging)
    gemm_bt<0><<<dim3(NQKV / 128, S_LEN / 128), 256, 0, stream>>>(xbf, Wq_t, Cmix, S_LEN, NQKV, HID);
    // 4) conv + silu + l2norm prep
    prep_kernel<<<S_LEN, 512, 0, stream>>>(Cmix, conv_w, beta, qn, kn, vb);
    // 5) per-chunk precompute (writes MFMA-layout tiles over dead Cmix)
    precomp_kernel<<<NCHUNK * HVN, 256, 0, stream>>>(qn, kn, vb, g, beta, bufB, bufK, egc, ekd, eg);
    // 6) z GEMM (over dead vb)
    gemm_bt<0><<<dim3(HID / 128, S_LEN / 128), 256, 0, stream>>>(xbf, Wz_t, Cz, S_LEN, HID, HID);
    // 7) MFMA sequential scan
    scan_kernel<<<HVN * 2, 256, 0, stream>>>(bufB, bufK, egc, ekd, eg, o_buf);
    // 8) gated rmsnorm (gated over dead bufB head)
    gate_kernel<<<S_LEN, 256, 0, stream>>>(o_buf, Cz, norm_w, gated);
    // 9) W_out transpose (over dead o_buf) + output projection -> fp32 d_out
    cvt_wT_kernel<<<dim3(HID / 64, HID / 64), 256, 0, stream>>>(W_out, Wout_t, HID, HID);
    gemm_bt<1><<<dim3(HID / 128, S_LEN / 128), 256, 0, stream>>>(gated, Wout_t, d_out, S_LEN, HID, HID);
}

// Round 3
// 1300.049 us; speedup vs baseline: 3.2375x; 1.3043x over previous
//
#include <hip/hip_runtime.h>

#define S_LEN 8192
#define HID 2048
#define HKN 8
#define HVN 16
#define DKD 128
#define DVD 128
#define NCHUNK 128
#define CLEN 64
#define NQKV 4096
#define EPSF 1e-6f

typedef unsigned int u32;
typedef unsigned short u16;
typedef __attribute__((ext_vector_type(8))) short s16x8;
typedef __attribute__((ext_vector_type(4))) float f32x4;

__device__ __forceinline__ float bfraw2f(u16 v) { return __uint_as_float(((u32)v) << 16); }
__device__ __forceinline__ u16 f2bf_rne(float f) {
    u32 u = __float_as_uint(f);
    u32 r = u + 0x7fffu + ((u >> 16) & 1u);
    return (u16)(r >> 16);
}
__device__ __forceinline__ void unpack8(uint4 u, float* f) {
    const u32 a[4] = {u.x, u.y, u.z, u.w};
#pragma unroll
    for (int q = 0; q < 4; ++q) {
        f[2*q]   = __uint_as_float(a[q] << 16);
        f[2*q+1] = __uint_as_float(a[q] & 0xffff0000u);
    }
}
__device__ __forceinline__ uint4 pack8(const float* v) {
    uint4 r;
    r.x = (u32)f2bf_rne(v[0]) | ((u32)f2bf_rne(v[1]) << 16);
    r.y = (u32)f2bf_rne(v[2]) | ((u32)f2bf_rne(v[3]) << 16);
    r.z = (u32)f2bf_rne(v[4]) | ((u32)f2bf_rne(v[5]) << 16);
    r.w = (u32)f2bf_rne(v[6]) | ((u32)f2bf_rne(v[7]) << 16);
    return r;
}

// async global->LDS staging (lane-strided 16B; LDS dest wave-uniform base + lane*16)
__device__ __forceinline__ void gload_lds16(const u16* g, u16* l) {
    __builtin_amdgcn_global_load_lds((const __attribute__((address_space(1))) unsigned int*)g,
                                     (__attribute__((address_space(3))) unsigned int*)l, 16, 0, 0);
}
__device__ __forceinline__ void gload_lds4(const float* g, u16* l) {
    __builtin_amdgcn_global_load_lds((const __attribute__((address_space(1))) unsigned int*)g,
                                     (__attribute__((address_space(3))) unsigned int*)l, 4, 0, 0);
}

// ------------- b,a projections (scalar, broadcast-x) + activations -------------
__global__ __launch_bounds__(256) void ba_kernel(const float* __restrict__ x,
                                                 const float* __restrict__ Wb,
                                                 const float* __restrict__ Wa,
                                                 const float* __restrict__ A_log,
                                                 const float* __restrict__ dt_bias,
                                                 float* __restrict__ beta,
                                                 float* __restrict__ g) {
    const int t = threadIdx.x;
    const int row = blockIdx.x * 8 + (t >> 5);
    const int c = t & 31;
    const int cc = c & 15;
    const float* W = (c < 16) ? Wb : Wa;
    const float* xr = x + (size_t)row * HID;
    float acc = 0.f;
    for (int k = 0; k < HID; ++k) acc = fmaf(xr[k], W[k * 16 + cc], acc);
    if (c < 16) {
        beta[row * 16 + cc] = 1.f / (1.f + expf(-acc));
    } else {
        float v = acc + dt_bias[cc];
        float sp = (v > 20.f) ? v : log1pf(expf(v));
        g[row * 16 + cc] = -expf(A_log[cc]) * sp;
    }
}

// ------------- fp32 -> bf16 bulk convert -------------
__global__ __launch_bounds__(256) void cvt_x_kernel(const float* __restrict__ x,
                                                    u16* __restrict__ xb) {
    const size_t i8 = ((size_t)blockIdx.x * 256 + threadIdx.x) << 3;
    float4 a = *(const float4*)(x + i8);
    float4 b = *(const float4*)(x + i8 + 4);
    float v[8] = {a.x, a.y, a.z, a.w, b.x, b.y, b.z, b.w};
    *(uint4*)(xb + i8) = pack8(v);
}

// ------------- W [K,N] fp32 -> Wt [N,K] bf16 (tiled transpose) -------------
__global__ __launch_bounds__(256) void cvt_wT_kernel(const float* __restrict__ W,
                                                     u16* __restrict__ Wt,
                                                     int N, int K) {
    __shared__ u16 T[64 * 72];
    const int t = threadIdx.x;
    const int n0 = blockIdx.x * 64;
    const int k0 = blockIdx.y * 64;
#pragma unroll
    for (int i = 0; i < 4; ++i) {
        int flat = i * 256 + t;
        int kr = flat >> 4, c4 = (flat & 15) << 2;  // 64 k-rows x 16 n-quads
        float4 v = *(const float4*)(W + (size_t)(k0 + kr) * N + n0 + c4);
        T[(c4 + 0) * 72 + kr] = f2bf_rne(v.x);
        T[(c4 + 1) * 72 + kr] = f2bf_rne(v.y);
        T[(c4 + 2) * 72 + kr] = f2bf_rne(v.z);
        T[(c4 + 3) * 72 + kr] = f2bf_rne(v.w);
    }
    __syncthreads();
#pragma unroll
    for (int i = 0; i < 2; ++i) {
        int flat = i * 256 + t;
        int n = flat >> 3, k8 = (flat & 7) << 3;    // 64 n-rows x 8 k-octs
        *(uint4*)(Wt + (size_t)(n0 + n) * K + k0 + k8) = *(const uint4*)(T + n * 72 + k8);
    }
}

// ------------- MFMA GEMM (m97 structure): C[M,N] = A[M,K] * Bt[N,K]^T, both bf16 -------------
template <int F32OUT>
__global__ __launch_bounds__(256) void gemm_bt(const u16* __restrict__ A,
                                               const u16* __restrict__ Bt,
                                               void* __restrict__ Cv,
                                               int M, int N, int K) {
    __shared__ __align__(16) u16 As[128 * 64];
    __shared__ __align__(16) u16 Bs[128 * 64];
    const int t = threadIdx.x;
    const int n0 = blockIdx.x * 128;
    const int m0 = blockIdx.y * 128;
    const int w = t >> 6, lane = t & 63;
    const int wm = (w >> 1) * 64, wn = (w & 1) * 64;
    const int ml = lane & 15, kq = lane >> 4;
    f32x4 acc[4][4];
#pragma unroll
    for (int i = 0; i < 4; ++i)
#pragma unroll
        for (int j = 0; j < 4; ++j) acc[i][j] = (f32x4){0.f, 0.f, 0.f, 0.f};

    for (int k0 = 0; k0 < K; k0 += 64) {
#pragma unroll
        for (int r = 0; r < 4; ++r) {
            int flat = r * 256 + t;
            int row = flat >> 3, kc = (flat & 7) << 3;
            gload_lds16(A  + (size_t)(m0 + row) * K + k0 + kc, As + flat * 8);
            gload_lds16(Bt + (size_t)(n0 + row) * K + k0 + kc, Bs + flat * 8);
        }
        __syncthreads();
#pragma unroll
        for (int ks = 0; ks < 2; ++ks) {
            s16x8 af[4], bfr[4];
#pragma unroll
            for (int mt = 0; mt < 4; ++mt)
                af[mt] = *(const s16x8*)(As + (wm + mt * 16 + ml) * 64 + ks * 32 + kq * 8);
#pragma unroll
            for (int nt = 0; nt < 4; ++nt)
                bfr[nt] = *(const s16x8*)(Bs + (wn + nt * 16 + ml) * 64 + ks * 32 + kq * 8);
#pragma unroll
            for (int mt = 0; mt < 4; ++mt)
#pragma unroll
                for (int nt = 0; nt < 4; ++nt)
                    acc[mt][nt] = __builtin_amdgcn_mfma_f32_16x16x32_bf16(af[mt], bfr[nt], acc[mt][nt], 0, 0, 0);
        }
        __syncthreads();
    }
#pragma unroll
    for (int mt = 0; mt < 4; ++mt)
#pragma unroll
        for (int nt = 0; nt < 4; ++nt)
#pragma unroll
            for (int r = 0; r < 4; ++r) {
                int row = m0 + wm + mt * 16 + kq * 4 + r;
                int col = n0 + wn + nt * 16 + ml;
                float v = acc[mt][nt][r];
                if (F32OUT)
                    ((float*)Cv)[(size_t)row * N + col] = v;
                else
                    ((u16*)Cv)[(size_t)row * N + col] = f2bf_rne(v);
            }
}

// ------------- conv(K=4) + silu + l2norm + beta-fold prep -------------
__global__ __launch_bounds__(512) void prep_kernel(const u16* __restrict__ Cmix,
                                                   const float* __restrict__ conv_w,
                                                   const float* __restrict__ beta,
                                                   u16* __restrict__ qn,
                                                   u16* __restrict__ kn,
                                                   u16* __restrict__ vb) {
    const int s = blockIdx.x;
    const int t = threadIdx.x;
    const int c8 = t << 3;
    __shared__ float ssq[16];
    if (t < 16) ssq[t] = 0.f;

    float y[8];
#pragma unroll
    for (int i = 0; i < 8; ++i) y[i] = 0.f;
    {
        uint4 mrow[4];
#pragma unroll
        for (int j = 0; j < 4; ++j) {
            int r = s - 3 + j;
            if (r >= 0) mrow[j] = *(const uint4*)(Cmix + (size_t)r * NQKV + c8);
            else        mrow[j] = uint4{0u, 0u, 0u, 0u};
        }
        float cw[8][4];
#pragma unroll
        for (int i = 0; i < 8; ++i) {
            float4 cv = *(const float4*)(conv_w + (size_t)(c8 + i) * 4);
            cw[i][0] = cv.x; cw[i][1] = cv.y; cw[i][2] = cv.z; cw[i][3] = cv.w;
        }
#pragma unroll
        for (int j = 0; j < 4; ++j) {
            float mf[8];
            unpack8(mrow[j], mf);
#pragma unroll
            for (int i = 0; i < 8; ++i) y[i] = fmaf(mf[i], cw[i][j], y[i]);
        }
#pragma unroll
        for (int i = 0; i < 8; ++i) {
            float v = y[i];
            y[i] = v / (1.f + expf(-v));
        }
    }
    __syncthreads();
    if (t < 256) {
        float p = 0.f;
#pragma unroll
        for (int i = 0; i < 8; ++i) p += y[i] * y[i];
        atomicAdd(&ssq[t >> 4], p);
    }
    __syncthreads();
    if (t < 128) {
        float rn = rsqrtf(ssq[t >> 4] + EPSF) * 0.08838834764831845f;
        float ov[8];
#pragma unroll
        for (int i = 0; i < 8; ++i) ov[i] = y[i] * rn;
        *(uint4*)(qn + (size_t)s * 1024 + c8) = pack8(ov);
    } else if (t < 256) {
        float rn = rsqrtf(ssq[t >> 4] + EPSF);
        float ov[8];
#pragma unroll
        for (int i = 0; i < 8; ++i) ov[i] = y[i] * rn;
        *(uint4*)(kn + (size_t)s * 1024 + (c8 - 1024)) = pack8(ov);
    } else {
        int vh = (c8 - 2048) >> 7;
        float bb = beta[s * 16 + vh];
        float ov[8];
#pragma unroll
        for (int i = 0; i < 8; ++i) ov[i] = y[i] * bb;
        *(uint4*)(vb + (size_t)s * 2048 + (c8 - 2048)) = pack8(ov);
    }
}

// ------------- per-(chunk,head) precompute — MFMA version -------------
// bufB per b (20480 u16): [ W[dv][c] 8192 | U(-u)[c][dk] swz 8192 | Aqk[i][j] swz 4096 ]
// bufK per bk=n*8+hs (16384 u16): [ qA[c][dk] swz 8192 | kA[dk][c] swz 8192 ]
// swizzle: 8-elem block index within row XOR'd with (row&7)
__global__ __launch_bounds__(256, 2) void precomp_kernel(const u16* __restrict__ qn,
                                                         const u16* __restrict__ kn,
                                                         const u16* __restrict__ vb,
                                                         const float* __restrict__ g,
                                                         const float* __restrict__ beta,
                                                         u16* __restrict__ bufB,
                                                         u16* __restrict__ bufK,
                                                         float* __restrict__ egc_arr,
                                                         float* __restrict__ ekd_arr,
                                                         float* __restrict__ eg) {
    const int b = blockIdx.x;  // n*16 + h
    const int n = b >> 4, h = b & 15, hs = h >> 1;
    const int t = threadIdx.x;
    const int s0 = n * 64;
    u16* BB = bufB + (size_t)b * 20480;

    __shared__ __align__(16) u16 sK[64 * 128];   // k  swz [c][d]
    __shared__ __align__(16) u16 sVQ[64 * 128];  // v swz [c][d] -> vT swz [d][c] (in place)
    __shared__ __align__(16) u16 sKT[64 * 128];  // kT swz [d][c]; then *bexp; then q swz [c][d]
    __shared__ __align__(16) float Am[64 * 64];  // A then T (fp32); then Tb bf16 overlay
    __shared__ float gc[64], bet[64], bexp[64];

    const int w = t >> 6, l = t & 63;
    const int l15 = l & 15, l4 = l >> 4;

    // ---- phase 0: load k, v (swizzled), gc/bet; gate scalars ----
#pragma unroll
    for (int i = 0; i < 4; ++i) {
        int flat = i * 256 + t;
        int c = flat >> 4, dc = (flat & 15) << 3;
        int sw = c * 128 + ((((dc >> 3) ^ (c & 7))) << 3);
        *(uint4*)(sK + sw)  = *(const uint4*)(kn + (size_t)(s0 + c) * 1024 + hs * 128 + dc);
        *(uint4*)(sVQ + sw) = *(const uint4*)(vb + (size_t)(s0 + c) * 2048 + h * 128 + dc);
    }
    if (t < 64) {
        gc[t] = g[(size_t)(s0 + t) * 16 + h];
        bet[t] = beta[(size_t)(s0 + t) * 16 + h];
    }
    __syncthreads();
    if (t == 0) {
        float run = 0.f;
        for (int c = 0; c < 64; ++c) { run += gc[c]; gc[c] = run; }
    }
    __syncthreads();
    if (t < 64) {
        float e = expf(gc[t]);
        float ek = expf(gc[63] - gc[t]);
        bexp[t] = bet[t] * e;
        egc_arr[b * 64 + t] = e;
        ekd_arr[b * 64 + t] = ek;
    }
    if (t == 0) eg[b] = expf(gc[63]);
    __syncthreads();

    // ---- phase 1: KK^T via MFMA -> Am; kT transpose -> sKT; v reads for in-place vT ----
    {
        s16x8 ak[4];
#pragma unroll
        for (int kk = 0; kk < 4; ++kk)
            ak[kk] = *(const s16x8*)(sK + (w * 16 + l15) * 128 + (((kk * 4 + l4) ^ (l15 & 7)) << 3));
        for (int nt = 0; nt <= w; ++nt) {
            f32x4 acc = (f32x4){0.f, 0.f, 0.f, 0.f};
#pragma unroll
            for (int kk = 0; kk < 4; ++kk) {
                s16x8 bk = *(const s16x8*)(sK + (nt * 16 + l15) * 128 + (((kk * 4 + l4) ^ (l15 & 7)) << 3));
                acc = __builtin_amdgcn_mfma_f32_16x16x32_bf16(ak[kk], bk, acc, 0, 0, 0);
            }
            const int j = nt * 16 + l15;
#pragma unroll
            for (int r = 0; r < 4; ++r) {
                int i = w * 16 + l4 * 4 + r;
                if (j < i) Am[i * 64 + j] = -acc[r] * bet[i] * expf(gc[i] - gc[j]);
            }
        }
    }
    uint4 vreg[4];
    {
        const int c = t & 63, db = t >> 6;
#pragma unroll
        for (int r = 0; r < 4; ++r) {
            uint4 kv = *(const uint4*)(sK + c * 128 + ((((4 * db + r) ^ (c & 7))) << 3));
            const u16* kp = (const u16*)&kv;
#pragma unroll
            for (int e = 0; e < 8; ++e) {
                int d = (4 * db + r) * 8 + e;
                sKT[d * 64 + ((((c >> 3) ^ (d & 7))) << 3) + (c & 7)] = kp[e];
            }
            vreg[r] = *(const uint4*)(sVQ + c * 128 + ((((4 * db + r) ^ (c & 7))) << 3));
        }
    }
    __syncthreads();

    // ---- phase 2a: write vT in place ----
    {
        const int c = t & 63, db = t >> 6;
#pragma unroll
        for (int r = 0; r < 4; ++r) {
            const u16* vp = (const u16*)&vreg[r];
#pragma unroll
            for (int e = 0; e < 8; ++e) {
                int d = (4 * db + r) * 8 + e;
                sVQ[d * 64 + ((((c >> 3) ^ (d & 7))) << 3) + (c & 7)] = vp[e];
            }
        }
    }
    __syncthreads();

    // ---- phase 2b: T = (I-A)^{-1}, per-column register recurrence (wave 0, no sync) ----
    if (t < 64) {
        float Tc[64];
#pragma unroll
        for (int i = 0; i < 64; ++i) {
            float val = (t == i) ? 1.f : 0.f;
#pragma unroll
            for (int j = 0; j < i; ++j) val = fmaf(Am[i * 64 + j], Tc[j], val);
            Tc[i] = val;
            Am[i * 64 + t] = val;
        }
    }
    __syncthreads();

    // ---- phase 3a: read T rows to regs; kA copy (pre-scale) + bexp-scale sKT ----
    float tv[16];
    {
        const int c = t >> 2, j0 = (t & 3) << 4;
#pragma unroll
        for (int q = 0; q < 16; ++q) tv[q] = Am[c * 64 + j0 + q];
    }
    {
        u16* KB = bufK + (size_t)((n << 3) + hs) * 16384;
#pragma unroll
        for (int i = 0; i < 4; ++i) {
            int f = t * 4 + i;  // 1024 uint4 covering sKT
            int d = f >> 3, sb = f & 7;
            uint4 v = *(const uint4*)(sKT + d * 64 + sb * 8);
            if ((h & 1) == 0) *(uint4*)(KB + 8192 + d * 64 + sb * 8) = v;
            int jb = ((sb ^ (d & 7)) << 3);
            float vf[8]; unpack8(v, vf);
#pragma unroll
            for (int e = 0; e < 8; ++e) vf[e] *= bexp[jb + e];
            *(uint4*)(sKT + d * 64 + sb * 8) = pack8(vf);
        }
    }
    __syncthreads();

    // ---- phase 3b: Tb bf16 swizzled (overlay on Am) ----
    {
        u16* Tb = (u16*)Am;
        const int c = t >> 2, j0 = (t & 3) << 4;
        uint4 p0 = pack8(tv), p1 = pack8(tv + 8);
        *(uint4*)(Tb + c * 64 + ((((j0 >> 3) ^ (c & 7))) << 3)) = p0;
        *(uint4*)(Tb + c * 64 + (((((j0 >> 3) + 1) ^ (c & 7))) << 3)) = p1;
    }
    __syncthreads();

    // ---- phase 4: u = (kT*bexp) x Tb -> -U[c][dk] swz ; w = Tb x vT -> W[dv][c] ----
    {
        const u16* Tb = (const u16*)Am;
#pragma unroll
        for (int fr2 = 0; fr2 < 2; ++fr2) {
            const int d = w * 32 + fr2 * 16 + l15;
            s16x8 au[2];
#pragma unroll
            for (int kk = 0; kk < 2; ++kk)
                au[kk] = *(const s16x8*)(sKT + d * 64 + (((kk * 4 + l4) ^ (d & 7)) << 3));
#pragma unroll
            for (int fc = 0; fc < 4; ++fc) {
                const int c = fc * 16 + l15;
                f32x4 acc = (f32x4){0.f, 0.f, 0.f, 0.f};
#pragma unroll
                for (int kk = 0; kk < 2; ++kk) {
                    s16x8 bt = *(const s16x8*)(Tb + c * 64 + (((kk * 4 + l4) ^ (c & 7)) << 3));
                    acc = __builtin_amdgcn_mfma_f32_16x16x32_bf16(au[kk], bt, acc, 0, 0, 0);
                }
                const int d0 = w * 32 + fr2 * 16 + l4 * 4;
                uint2 pr;
                pr.x = (u32)f2bf_rne(-acc[0]) | ((u32)f2bf_rne(-acc[1]) << 16);
                pr.y = (u32)f2bf_rne(-acc[2]) | ((u32)f2bf_rne(-acc[3]) << 16);
                *(uint2*)(BB + 8192 + c * 128 + (((d0 >> 3) ^ (c & 7)) << 3) + (d0 & 7)) = pr;
            }
        }
#pragma unroll
        for (int fc2 = 0; fc2 < 2; ++fc2) {
            const int dv = w * 32 + fc2 * 16 + l15;
            s16x8 bv[2];
#pragma unroll
            for (int kk = 0; kk < 2; ++kk)
                bv[kk] = *(const s16x8*)(sVQ + dv * 64 + (((kk * 4 + l4) ^ (dv & 7)) << 3));
#pragma unroll
            for (int fr = 0; fr < 4; ++fr) {
                const int c = fr * 16 + l15;
                f32x4 acc = (f32x4){0.f, 0.f, 0.f, 0.f};
#pragma unroll
                for (int kk = 0; kk < 2; ++kk) {
                    s16x8 at = *(const s16x8*)(Tb + c * 64 + (((kk * 4 + l4) ^ (c & 7)) << 3));
                    acc = __builtin_amdgcn_mfma_f32_16x16x32_bf16(at, bv[kk], acc, 0, 0, 0);
                }
                const int c0 = fr * 16 + l4 * 4;
                uint2 pr;
                pr.x = (u32)f2bf_rne(acc[0]) | ((u32)f2bf_rne(acc[1]) << 16);
                pr.y = (u32)f2bf_rne(acc[2]) | ((u32)f2bf_rne(acc[3]) << 16);
                *(uint2*)(BB + dv * 64 + c0) = pr;
            }
        }
    }
    __syncthreads();

    // ---- phase 5: load q into sKT space (swizzled [c][d]) ----
#pragma unroll
    for (int i = 0; i < 4; ++i) {
        int flat = i * 256 + t;
        int c = flat >> 4, dc = (flat & 15) << 3;
        *(uint4*)(sKT + c * 128 + ((((dc >> 3) ^ (c & 7))) << 3)) =
            *(const uint4*)(qn + (size_t)(s0 + c) * 1024 + hs * 128 + dc);
    }
    __syncthreads();

    // ---- phase 6: Aqk = q x k^T (masked, gated) -> BB; qA copy ----
    {
        const u16* sQ = sKT;
        s16x8 aq[4];
#pragma unroll
        for (int kk = 0; kk < 4; ++kk)
            aq[kk] = *(const s16x8*)(sQ + (w * 16 + l15) * 128 + (((kk * 4 + l4) ^ (l15 & 7)) << 3));
#pragma unroll
        for (int nt = 0; nt < 4; ++nt) {
            f32x4 acc = (f32x4){0.f, 0.f, 0.f, 0.f};
            if (nt <= w) {
#pragma unroll
                for (int kk = 0; kk < 4; ++kk) {
                    s16x8 bk = *(const s16x8*)(sK + (nt * 16 + l15) * 128 + (((kk * 4 + l4) ^ (l15 & 7)) << 3));
                    acc = __builtin_amdgcn_mfma_f32_16x16x32_bf16(aq[kk], bk, acc, 0, 0, 0);
                }
            }
            const int jj = nt * 16 + l15;
#pragma unroll
            for (int r = 0; r < 4; ++r) {
                const int i = w * 16 + l4 * 4 + r;
                float val = 0.f;
                if (nt < w || (nt == w && jj <= i)) val = acc[r] * expf(gc[i] - gc[jj]);
                BB[16384 + i * 64 + (((jj >> 3) ^ (i & 7)) << 3) + (jj & 7)] = f2bf_rne(val);
            }
        }
        if ((h & 1) == 0) {
            u16* KB = bufK + (size_t)((n << 3) + hs) * 16384;
#pragma unroll
            for (int i = 0; i < 4; ++i) {
                int f = i * 256 + t;
                int c = f >> 4, sb = f & 15;
                *(uint4*)(KB + c * 128 + sb * 8) = *(const uint4*)(sQ + c * 128 + sb * 8);
            }
        }
    }
}

// ------------- MFMA sequential inter-chunk scan -------------
#define STG 28928
#define OFF_AQK 8192
#define OFF_QA 12288
#define OFF_KA 20480
#define OFF_EGC 28672
#define OFF_EKD 28800

__global__ __launch_bounds__(256, 1) void scan_kernel(const u16* __restrict__ bufB,
                                                      const u16* __restrict__ bufK,
                                                      const float* __restrict__ egc_g,
                                                      const float* __restrict__ ekd_g,
                                                      const float* __restrict__ eg_g,
                                                      u16* __restrict__ o) {
    __shared__ __align__(16) u16 sStage[2 * STG];
    __shared__ __align__(16) u16 sSTb[4][16 * 136];
    __shared__ __align__(16) u16 sVT[4][16 * 72];
    __shared__ __align__(16) u16 sVTs[4][16 * 72];

    const int h = blockIdx.x >> 1;
    const int dvh = (blockIdx.x & 1) << 6;
    const int hs = h >> 1;
    const int w = threadIdx.x >> 6;
    const int l = threadIdx.x & 63;
    const int l15 = l & 15, l4 = l >> 4, l7 = l & 7;
    const int dv0 = dvh + (w << 4);

    u16* STb = sSTb[w];
    u16* VT  = sVT[w];
    u16* VTs = sVTs[w];

    for (int i = l; i < 16 * 136; i += 64) STb[i] = 0;

    f32x4 Sreg[8];
#pragma unroll
    for (int i = 0; i < 8; ++i) Sreg[i] = (f32x4){0.f, 0.f, 0.f, 0.f};

    auto stage = [&](int n2, u16* dst) {
        const int b2 = (n2 << 4) + h;
        const u16* sA = bufB + (size_t)b2 * 20480 + 8192 + (w * 3072 + l * 8);
        u16* dA = dst + w * 3072;
#pragma unroll
        for (int i = 0; i < 6; ++i) gload_lds16(sA + i * 512, dA + i * 512);
        const u16* sB = bufK + (size_t)((n2 << 3) + hs) * 16384 + (w * 4096 + l * 8);
        u16* dB = dst + 12288 + w * 4096;
#pragma unroll
        for (int i = 0; i < 8; ++i) gload_lds16(sB + i * 512, dB + i * 512);
        if (w == 0) gload_lds4(egc_g + (b2 << 6) + l, dst + OFF_EGC);
        else if (w == 1) gload_lds4(ekd_g + (b2 << 6) + l, dst + OFF_EKD);
    };
    auto loadW = [&](int n2, uint2 (&wr)[4]) {
        const u16* wb = bufB + (size_t)((n2 << 4) + h) * 20480 + (size_t)(dv0 + l15) * 64 + l4 * 4;
#pragma unroll
        for (int mt = 0; mt < 4; ++mt) wr[mt] = *(const uint2*)(wb + mt * 16);
    };

    uint2 wA[4], wB[4];
    float egA, egB;
    stage(0, sStage);
    loadW(0, wA);
    egA = eg_g[h];
    __syncthreads();

    int cur = 0;
    for (int n = 0; n < NCHUNK; ++n) {
        const u16* buf = sStage + cur * STG;
        if (n + 1 < NCHUNK) {
            stage(n + 1, sStage + (cur ^ 1) * STG);
            loadW(n + 1, wB);
            egB = eg_g[((n + 1) << 4) + h];
        }
        const u16* bU = buf;
        const u16* bA = buf + OFF_AQK;
        const u16* bQ = buf + OFF_QA;
        const u16* bK = buf + OFF_KA;
        const float* egc = (const float*)(buf + OFF_EGC);
        const float* ekd = (const float*)(buf + OFF_EKD);

        s16x8 bF[4];
#pragma unroll
        for (int kk = 0; kk < 4; ++kk)
            bF[kk] = *(const s16x8*)(STb + l15 * 136 + kk * 32 + l4 * 8);

        f32x4 V[4];
#pragma unroll
        for (int mt = 0; mt < 4; ++mt) {
            V[mt][0] = bfraw2f((u16)(wA[mt].x & 0xffffu));
            V[mt][1] = bfraw2f((u16)(wA[mt].x >> 16));
            V[mt][2] = bfraw2f((u16)(wA[mt].y & 0xffffu));
            V[mt][3] = bfraw2f((u16)(wA[mt].y >> 16));
        }
#pragma unroll
        for (int kk = 0; kk < 4; ++kk) {
            const int sw = ((kk * 4 + l4) ^ l7) << 3;
#pragma unroll
            for (int mt = 0; mt < 4; ++mt) {
                s16x8 a = *(const s16x8*)(bU + (mt * 16 + l15) * 128 + sw);
                V[mt] = __builtin_amdgcn_mfma_f32_16x16x32_bf16(a, bF[kk], V[mt], 0, 0, 0);
            }
        }

        f32x4 O[4];
#pragma unroll
        for (int mt = 0; mt < 4; ++mt) O[mt] = (f32x4){0.f, 0.f, 0.f, 0.f};
#pragma unroll
        for (int kk = 0; kk < 4; ++kk) {
            const int sw = ((kk * 4 + l4) ^ l7) << 3;
#pragma unroll
            for (int mt = 0; mt < 4; ++mt) {
                s16x8 a = *(const s16x8*)(bQ + (mt * 16 + l15) * 128 + sw);
                O[mt] = __builtin_amdgcn_mfma_f32_16x16x32_bf16(a, bF[kk], O[mt], 0, 0, 0);
            }
        }
#pragma unroll
        for (int mt = 0; mt < 4; ++mt)
#pragma unroll
            for (int r = 0; r < 4; ++r) O[mt][r] *= egc[mt * 16 + l4 * 4 + r];

#pragma unroll
        for (int mt = 0; mt < 4; ++mt) {
            const int cb = mt * 16 + l4 * 4;
            uint2 uv, us;
            uv.x = (u32)f2bf_rne(V[mt][0]) | ((u32)f2bf_rne(V[mt][1]) << 16);
            uv.y = (u32)f2bf_rne(V[mt][2]) | ((u32)f2bf_rne(V[mt][3]) << 16);
            us.x = (u32)f2bf_rne(V[mt][0] * ekd[cb]) | ((u32)f2bf_rne(V[mt][1] * ekd[cb + 1]) << 16);
            us.y = (u32)f2bf_rne(V[mt][2] * ekd[cb + 2]) | ((u32)f2bf_rne(V[mt][3] * ekd[cb + 3]) << 16);
            *(uint2*)(VT + l15 * 72 + cb) = uv;
            *(uint2*)(VTs + l15 * 72 + cb) = us;
        }

        s16x8 vF0 = *(const s16x8*)(VT + l15 * 72 + l4 * 8);
        s16x8 vF1 = *(const s16x8*)(VT + l15 * 72 + 32 + l4 * 8);
#pragma unroll
        for (int mt = 0; mt < 4; ++mt) {
            s16x8 a = *(const s16x8*)(bA + (mt * 16 + l15) * 64 + ((l4 ^ l7) << 3));
            O[mt] = __builtin_amdgcn_mfma_f32_16x16x32_bf16(a, vF0, O[mt], 0, 0, 0);
        }
#pragma unroll
        for (int mt = 0; mt < 4; ++mt) {
            s16x8 a = *(const s16x8*)(bA + (mt * 16 + l15) * 64 + (((4 + l4) ^ l7) << 3));
            O[mt] = __builtin_amdgcn_mfma_f32_16x16x32_bf16(a, vF1, O[mt], 0, 0, 0);
        }

        const int s0 = n << 6;
#pragma unroll
        for (int mt = 0; mt < 4; ++mt)
#pragma unroll
            for (int r = 0; r < 4; ++r)
                o[(size_t)(s0 + mt * 16 + l4 * 4 + r) * 2048 + (h << 7) + dv0 + l15] = f2bf_rne(O[mt][r]);

        s16x8 sF0 = *(const s16x8*)(VTs + l15 * 72 + l4 * 8);
        s16x8 sF1 = *(const s16x8*)(VTs + l15 * 72 + 32 + l4 * 8);
#pragma unroll
        for (int nt = 0; nt < 8; ++nt) {
#pragma unroll
            for (int r = 0; r < 4; ++r) Sreg[nt][r] *= egA;
            s16x8 a0 = *(const s16x8*)(bK + (nt * 16 + l15) * 64 + ((l4 ^ l7) << 3));
            Sreg[nt] = __builtin_amdgcn_mfma_f32_16x16x32_bf16(a0, sF0, Sreg[nt], 0, 0, 0);
            s16x8 a1 = *(const s16x8*)(bK + (nt * 16 + l15) * 64 + (((4 + l4) ^ l7) << 3));
            Sreg[nt] = __builtin_amdgcn_mfma_f32_16x16x32_bf16(a1, sF1, Sreg[nt], 0, 0, 0);
        }
#pragma unroll
        for (int nt = 0; nt < 8; ++nt) {
            uint2 sv;
            sv.x = (u32)f2bf_rne(Sreg[nt][0]) | ((u32)f2bf_rne(Sreg[nt][1]) << 16);
            sv.y = (u32)f2bf_rne(Sreg[nt][2]) | ((u32)f2bf_rne(Sreg[nt][3]) << 16);
            *(uint2*)(STb + l15 * 136 + nt * 16 + l4 * 4) = sv;
        }
        __syncthreads();
#pragma unroll
        for (int i = 0; i < 4; ++i) wA[i] = wB[i];
        egA = egB;
        cur ^= 1;
    }
}

// ------------- gated rmsnorm * silu(z) -> bf16 -------------
__global__ __launch_bounds__(256) void gate_kernel(const u16* __restrict__ o,
                                                   const u16* __restrict__ Cz,
                                                   const float* __restrict__ norm_w,
                                                   u16* __restrict__ gated) {
    const int s = blockIdx.x, t = threadIdx.x;
    const int c8 = t << 3, hh = t >> 4;
    __shared__ float ssq[16];
    if (t < 16) ssq[t] = 0.f;
    float ov[8];
    unpack8(*(const uint4*)(o + (size_t)s * 2048 + c8), ov);
    float p = 0.f;
#pragma unroll
    for (int i = 0; i < 8; ++i) p += ov[i] * ov[i];
    __syncthreads();
    atomicAdd(&ssq[hh], p);
    __syncthreads();
    const float rms = rsqrtf(ssq[hh] * 0.0078125f + EPSF);
    float zf[8];
    unpack8(*(const uint4*)(Cz + (size_t)s * 2048 + c8), zf);
    const int d0 = c8 & 127;
    float res[8];
#pragma unroll
    for (int i = 0; i < 8; ++i) {
        float z = zf[i];
        float sz = z / (1.f + expf(-z));
        res[i] = ov[i] * rms * norm_w[d0 + i] * sz;
    }
    *(uint4*)(gated + (size_t)s * 2048 + c8) = pack8(res);
}

extern "C" void kernel_launch(void* const* d_in, const int* in_sizes, int n_in,
                              void* d_out, int out_size, void* d_ws, size_t ws_size,
                              hipStream_t stream) {
    (void)in_sizes; (void)n_in; (void)out_size; (void)ws_size;
    const float* x       = (const float*)d_in[0];
    const float* W_qkv   = (const float*)d_in[1];
    const float* W_z     = (const float*)d_in[2];
    const float* W_b     = (const float*)d_in[3];
    const float* W_a     = (const float*)d_in[4];
    const float* conv_w  = (const float*)d_in[5];
    const float* A_log   = (const float*)d_in[6];
    const float* dt_bias = (const float*)d_in[7];
    const float* norm_w  = (const float*)d_in[8];
    const float* W_out   = (const float*)d_in[9];

    char* p = (char*)d_ws;
    auto alloc = [&](size_t bytes) {
        char* r = p;
        p += (bytes + 255) & ~(size_t)255;
        return r;
    };
    u16* Cmix    = (u16*)alloc((size_t)S_LEN * NQKV * 2);       // 67.1 MB (dead after prep)
    char* extra  = alloc((size_t)50331648); (void)extra;        // 50.3 MB (bufB/bufK tail)
    u16* qn      = (u16*)alloc((size_t)S_LEN * HKN * DKD * 2);  // 16.8 MB
    u16* kn      = (u16*)alloc((size_t)S_LEN * HKN * DKD * 2);  // 16.8 MB
    u16* vb      = (u16*)alloc((size_t)S_LEN * HVN * DVD * 2);  // 33.5 MB
    float* egc   = (float*)alloc((size_t)NCHUNK * HVN * CLEN * 4);
    float* ekd   = (float*)alloc((size_t)NCHUNK * HVN * CLEN * 4);
    float* eg    = (float*)alloc((size_t)NCHUNK * HVN * 4);
    float* beta  = (float*)alloc((size_t)S_LEN * HVN * 4);
    float* g     = (float*)alloc((size_t)S_LEN * HVN * 4);
    // lifetime-disjoint overlays:
    u16* bufB  = Cmix;
    u16* bufK  = (u16*)((char*)Cmix + (size_t)83886080);
    u16* o_buf = qn;
    u16* Cz    = vb;
    u16* gated = Cmix;
    // bf16 operand scratch inside d_out (dead before final GEMM writes d_out):
    u16* xbf    = (u16*)d_out;
    u16* Wq_t   = (u16*)d_out + (size_t)16777216;
    u16* Wz_t   = (u16*)d_out + (size_t)25165824;
    u16* Wout_t = qn;

    ba_kernel<<<S_LEN / 8, 256, 0, stream>>>(x, W_b, W_a, A_log, dt_bias, beta, g);
    cvt_x_kernel<<<S_LEN * HID / (256 * 8), 256, 0, stream>>>(x, xbf);
    cvt_wT_kernel<<<dim3(NQKV / 64, HID / 64), 256, 0, stream>>>(W_qkv, Wq_t, NQKV, HID);
    cvt_wT_kernel<<<dim3(HID / 64, HID / 64), 256, 0, stream>>>(W_z, Wz_t, HID, HID);
    gemm_bt<0><<<dim3(NQKV / 128, S_LEN / 128), 256, 0, stream>>>(xbf, Wq_t, Cmix, S_LEN, NQKV, HID);
    prep_kernel<<<S_LEN, 512, 0, stream>>>(Cmix, conv_w, beta, qn, kn, vb);
    precomp_kernel<<<NCHUNK * HVN, 256, 0, stream>>>(qn, kn, vb, g, beta, bufB, bufK, egc, ekd, eg);
    gemm_bt<0><<<dim3(HID / 128, S_LEN / 128), 256, 0, stream>>>(xbf, Wz_t, Cz, S_LEN, HID, HID);
    scan_kernel<<<HVN * 2, 256, 0, stream>>>(bufB, bufK, egc, ekd, eg, o_buf);
    gate_kernel<<<S_LEN, 256, 0, stream>>>(o_buf, Cz, norm_w, gated);
    cvt_wT_kernel<<<dim3(HID / 64, HID / 64), 256, 0, stream>>>(W_out, Wout_t, HID, HID);
    gemm_bt<1><<<dim3(HID / 128, S_LEN / 128), 256, 0, stream>>>(gated, Wout_t, d_out, S_LEN, HID, HID);
}

// Round 5
// 1227.427 us; speedup vs baseline: 3.4290x; 1.0592x over previous
//
#include <hip/hip_runtime.h>

#define S_LEN 8192
#define HID 2048
#define HKN 8
#define HVN 16
#define DKD 128
#define DVD 128
#define NCHUNK 128
#define CLEN 64
#define NQKV 4096
#define EPSF 1e-6f

typedef unsigned int u32;
typedef unsigned short u16;
typedef __attribute__((ext_vector_type(8))) short s16x8;
typedef __attribute__((ext_vector_type(4))) float f32x4;

__device__ __forceinline__ float bfraw2f(u16 v) { return __uint_as_float(((u32)v) << 16); }
__device__ __forceinline__ u16 f2bf_rne(float f) {
    u32 u = __float_as_uint(f);
    u32 r = u + 0x7fffu + ((u >> 16) & 1u);
    return (u16)(r >> 16);
}
__device__ __forceinline__ void unpack8(uint4 u, float* f) {
    const u32 a[4] = {u.x, u.y, u.z, u.w};
#pragma unroll
    for (int q = 0; q < 4; ++q) {
        f[2*q]   = __uint_as_float(a[q] << 16);
        f[2*q+1] = __uint_as_float(a[q] & 0xffff0000u);
    }
}
__device__ __forceinline__ uint4 pack8(const float* v) {
    uint4 r;
    r.x = (u32)f2bf_rne(v[0]) | ((u32)f2bf_rne(v[1]) << 16);
    r.y = (u32)f2bf_rne(v[2]) | ((u32)f2bf_rne(v[3]) << 16);
    r.z = (u32)f2bf_rne(v[4]) | ((u32)f2bf_rne(v[5]) << 16);
    r.w = (u32)f2bf_rne(v[6]) | ((u32)f2bf_rne(v[7]) << 16);
    return r;
}

// async global->LDS staging (lane-strided 16B; LDS dest wave-uniform base + lane*16)
__device__ __forceinline__ void gload_lds16(const u16* g, u16* l) {
    __builtin_amdgcn_global_load_lds((const __attribute__((address_space(1))) unsigned int*)g,
                                     (__attribute__((address_space(3))) unsigned int*)l, 16, 0, 0);
}
__device__ __forceinline__ void gload_lds4(const float* g, u16* l) {
    __builtin_amdgcn_global_load_lds((const __attribute__((address_space(1))) unsigned int*)g,
                                     (__attribute__((address_space(3))) unsigned int*)l, 4, 0, 0);
}

// ------------- b,a projections (scalar, broadcast-x) + activations -------------
__global__ __launch_bounds__(256) void ba_kernel(const float* __restrict__ x,
                                                 const float* __restrict__ Wb,
                                                 const float* __restrict__ Wa,
                                                 const float* __restrict__ A_log,
                                                 const float* __restrict__ dt_bias,
                                                 float* __restrict__ beta,
                                                 float* __restrict__ g) {
    const int t = threadIdx.x;
    const int row = blockIdx.x * 8 + (t >> 5);
    const int c = t & 31;
    const int cc = c & 15;
    const float* W = (c < 16) ? Wb : Wa;
    const float* xr = x + (size_t)row * HID;
    float acc = 0.f;
    for (int k = 0; k < HID; ++k) acc = fmaf(xr[k], W[k * 16 + cc], acc);
    if (c < 16) {
        beta[row * 16 + cc] = 1.f / (1.f + expf(-acc));
    } else {
        float v = acc + dt_bias[cc];
        float sp = (v > 20.f) ? v : log1pf(expf(v));
        g[row * 16 + cc] = -expf(A_log[cc]) * sp;
    }
}

// ------------- fp32 -> bf16 bulk convert -------------
__global__ __launch_bounds__(256) void cvt_x_kernel(const float* __restrict__ x,
                                                    u16* __restrict__ xb) {
    const size_t i8 = ((size_t)blockIdx.x * 256 + threadIdx.x) << 3;
    float4 a = *(const float4*)(x + i8);
    float4 b = *(const float4*)(x + i8 + 4);
    float v[8] = {a.x, a.y, a.z, a.w, b.x, b.y, b.z, b.w};
    *(uint4*)(xb + i8) = pack8(v);
}

// ------------- W [K,N] fp32 -> Wt [N,K] bf16 (tiled transpose) -------------
__global__ __launch_bounds__(256) void cvt_wT_kernel(const float* __restrict__ W,
                                                     u16* __restrict__ Wt,
                                                     int N, int K) {
    __shared__ u16 T[64 * 72];
    const int t = threadIdx.x;
    const int n0 = blockIdx.x * 64;
    const int k0 = blockIdx.y * 64;
#pragma unroll
    for (int i = 0; i < 4; ++i) {
        int flat = i * 256 + t;
        int kr = flat >> 4, c4 = (flat & 15) << 2;
        float4 v = *(const float4*)(W + (size_t)(k0 + kr) * N + n0 + c4);
        T[(c4 + 0) * 72 + kr] = f2bf_rne(v.x);
        T[(c4 + 1) * 72 + kr] = f2bf_rne(v.y);
        T[(c4 + 2) * 72 + kr] = f2bf_rne(v.z);
        T[(c4 + 3) * 72 + kr] = f2bf_rne(v.w);
    }
    __syncthreads();
#pragma unroll
    for (int i = 0; i < 2; ++i) {
        int flat = i * 256 + t;
        int n = flat >> 3, k8 = (flat & 7) << 3;
        *(uint4*)(Wt + (size_t)(n0 + n) * K + k0 + k8) = *(const uint4*)(T + n * 72 + k8);
    }
}

// ------------- MFMA GEMM (m97 structure + XCD swizzle): C = A * Bt^T -------------
template <int F32OUT>
__global__ __launch_bounds__(256) void gemm_bt(const u16* __restrict__ A,
                                               const u16* __restrict__ Bt,
                                               void* __restrict__ Cv,
                                               int M, int N, int K) {
    __shared__ __align__(16) u16 As[128 * 64];
    __shared__ __align__(16) u16 Bs[128 * 64];
    const int t = threadIdx.x;
    // XCD-aware bijective swizzle (nwg % 8 == 0 for all our grids)
    const int nwg = gridDim.x * gridDim.y;
    int bid = blockIdx.y * gridDim.x + blockIdx.x;
    bid = (bid & 7) * (nwg >> 3) + (bid >> 3);
    const int n0 = (bid % gridDim.x) * 128;
    const int m0 = (bid / gridDim.x) * 128;
    const int w = t >> 6, lane = t & 63;
    const int wm = (w >> 1) * 64, wn = (w & 1) * 64;
    const int ml = lane & 15, kq = lane >> 4;
    f32x4 acc[4][4];
#pragma unroll
    for (int i = 0; i < 4; ++i)
#pragma unroll
        for (int j = 0; j < 4; ++j) acc[i][j] = (f32x4){0.f, 0.f, 0.f, 0.f};

    for (int k0 = 0; k0 < K; k0 += 64) {
#pragma unroll
        for (int r = 0; r < 4; ++r) {
            int flat = r * 256 + t;
            int row = flat >> 3, kc = (flat & 7) << 3;
            gload_lds16(A  + (size_t)(m0 + row) * K + k0 + kc, As + flat * 8);
            gload_lds16(Bt + (size_t)(n0 + row) * K + k0 + kc, Bs + flat * 8);
        }
        __syncthreads();
#pragma unroll
        for (int ks = 0; ks < 2; ++ks) {
            s16x8 af[4], bfr[4];
#pragma unroll
            for (int mt = 0; mt < 4; ++mt)
                af[mt] = *(const s16x8*)(As + (wm + mt * 16 + ml) * 64 + ks * 32 + kq * 8);
#pragma unroll
            for (int nt = 0; nt < 4; ++nt)
                bfr[nt] = *(const s16x8*)(Bs + (wn + nt * 16 + ml) * 64 + ks * 32 + kq * 8);
#pragma unroll
            for (int mt = 0; mt < 4; ++mt)
#pragma unroll
                for (int nt = 0; nt < 4; ++nt)
                    acc[mt][nt] = __builtin_amdgcn_mfma_f32_16x16x32_bf16(af[mt], bfr[nt], acc[mt][nt], 0, 0, 0);
        }
        __syncthreads();
    }
#pragma unroll
    for (int mt = 0; mt < 4; ++mt)
#pragma unroll
        for (int nt = 0; nt < 4; ++nt)
#pragma unroll
            for (int r = 0; r < 4; ++r) {
                int row = m0 + wm + mt * 16 + kq * 4 + r;
                int col = n0 + wn + nt * 16 + ml;
                float v = acc[mt][nt][r];
                if (F32OUT)
                    ((float*)Cv)[(size_t)row * N + col] = v;
                else
                    ((u16*)Cv)[(size_t)row * N + col] = f2bf_rne(v);
            }
}

// ------------- conv(K=4) + silu + l2norm + beta-fold prep -------------
__global__ __launch_bounds__(512) void prep_kernel(const u16* __restrict__ Cmix,
                                                   const float* __restrict__ conv_w,
                                                   const float* __restrict__ beta,
                                                   u16* __restrict__ qn,
                                                   u16* __restrict__ kn,
                                                   u16* __restrict__ vb) {
    const int s = blockIdx.x;
    const int t = threadIdx.x;
    const int c8 = t << 3;
    __shared__ float ssq[16];
    if (t < 16) ssq[t] = 0.f;

    float y[8];
#pragma unroll
    for (int i = 0; i < 8; ++i) y[i] = 0.f;
    {
        uint4 mrow[4];
#pragma unroll
        for (int j = 0; j < 4; ++j) {
            int r = s - 3 + j;
            if (r >= 0) mrow[j] = *(const uint4*)(Cmix + (size_t)r * NQKV + c8);
            else        mrow[j] = uint4{0u, 0u, 0u, 0u};
        }
        float cw[8][4];
#pragma unroll
        for (int i = 0; i < 8; ++i) {
            float4 cv = *(const float4*)(conv_w + (size_t)(c8 + i) * 4);
            cw[i][0] = cv.x; cw[i][1] = cv.y; cw[i][2] = cv.z; cw[i][3] = cv.w;
        }
#pragma unroll
        for (int j = 0; j < 4; ++j) {
            float mf[8];
            unpack8(mrow[j], mf);
#pragma unroll
            for (int i = 0; i < 8; ++i) y[i] = fmaf(mf[i], cw[i][j], y[i]);
        }
#pragma unroll
        for (int i = 0; i < 8; ++i) {
            float v = y[i];
            y[i] = v / (1.f + expf(-v));
        }
    }
    __syncthreads();
    if (t < 256) {
        float p = 0.f;
#pragma unroll
        for (int i = 0; i < 8; ++i) p += y[i] * y[i];
        atomicAdd(&ssq[t >> 4], p);
    }
    __syncthreads();
    if (t < 128) {
        float rn = rsqrtf(ssq[t >> 4] + EPSF) * 0.08838834764831845f;
        float ov[8];
#pragma unroll
        for (int i = 0; i < 8; ++i) ov[i] = y[i] * rn;
        *(uint4*)(qn + (size_t)s * 1024 + c8) = pack8(ov);
    } else if (t < 256) {
        float rn = rsqrtf(ssq[t >> 4] + EPSF);
        float ov[8];
#pragma unroll
        for (int i = 0; i < 8; ++i) ov[i] = y[i] * rn;
        *(uint4*)(kn + (size_t)s * 1024 + (c8 - 1024)) = pack8(ov);
    } else {
        int vh = (c8 - 2048) >> 7;
        float bb = beta[s * 16 + vh];
        float ov[8];
#pragma unroll
        for (int i = 0; i < 8; ++i) ov[i] = y[i] * bb;
        *(uint4*)(vb + (size_t)s * 2048 + (c8 - 2048)) = pack8(ov);
    }
}

// ------------- per-(chunk,head) precompute — MFMA version -------------
// bufB per b (20480 u16): [ W[dv][c] 8192 | U(-u)[c][dk] swz 8192 | Aqk[i][j] swz 4096 ]
// bufK per bk=n*8+hs (16384 u16): [ qA[c][dk] swz 8192 | kA[dk][c] swz 8192 ]
__global__ __launch_bounds__(256, 2) void precomp_kernel(const u16* __restrict__ qn,
                                                         const u16* __restrict__ kn,
                                                         const u16* __restrict__ vb,
                                                         const float* __restrict__ g,
                                                         const float* __restrict__ beta,
                                                         u16* __restrict__ bufB,
                                                         u16* __restrict__ bufK,
                                                         float* __restrict__ egc_arr,
                                                         float* __restrict__ ekd_arr,
                                                         float* __restrict__ eg) {
    const int b = blockIdx.x;  // n*16 + h
    const int n = b >> 4, h = b & 15, hs = h >> 1;
    const int t = threadIdx.x;
    const int s0 = n * 64;
    u16* BB = bufB + (size_t)b * 20480;

    __shared__ __align__(16) u16 sK[64 * 128];
    __shared__ __align__(16) u16 sVQ[64 * 128];
    __shared__ __align__(16) u16 sKT[64 * 128];
    __shared__ __align__(16) float Am[64 * 64];
    __shared__ float gc[64], bet[64], bexp[64];

    const int w = t >> 6, l = t & 63;
    const int l15 = l & 15, l4 = l >> 4;

#pragma unroll
    for (int i = 0; i < 4; ++i) {
        int flat = i * 256 + t;
        int c = flat >> 4, dc = (flat & 15) << 3;
        int sw = c * 128 + ((((dc >> 3) ^ (c & 7))) << 3);
        *(uint4*)(sK + sw)  = *(const uint4*)(kn + (size_t)(s0 + c) * 1024 + hs * 128 + dc);
        *(uint4*)(sVQ + sw) = *(const uint4*)(vb + (size_t)(s0 + c) * 2048 + h * 128 + dc);
    }
    if (t < 64) {
        gc[t] = g[(size_t)(s0 + t) * 16 + h];
        bet[t] = beta[(size_t)(s0 + t) * 16 + h];
    }
    __syncthreads();
    if (t == 0) {
        float run = 0.f;
        for (int c = 0; c < 64; ++c) { run += gc[c]; gc[c] = run; }
    }
    __syncthreads();
    if (t < 64) {
        float e = expf(gc[t]);
        float ek = expf(gc[63] - gc[t]);
        bexp[t] = bet[t] * e;
        egc_arr[b * 64 + t] = e;
        ekd_arr[b * 64 + t] = ek;
    }
    if (t == 0) eg[b] = expf(gc[63]);
    __syncthreads();

    {
        s16x8 ak[4];
#pragma unroll
        for (int kk = 0; kk < 4; ++kk)
            ak[kk] = *(const s16x8*)(sK + (w * 16 + l15) * 128 + (((kk * 4 + l4) ^ (l15 & 7)) << 3));
        for (int nt = 0; nt <= w; ++nt) {
            f32x4 acc = (f32x4){0.f, 0.f, 0.f, 0.f};
#pragma unroll
            for (int kk = 0; kk < 4; ++kk) {
                s16x8 bk = *(const s16x8*)(sK + (nt * 16 + l15) * 128 + (((kk * 4 + l4) ^ (l15 & 7)) << 3));
                acc = __builtin_amdgcn_mfma_f32_16x16x32_bf16(ak[kk], bk, acc, 0, 0, 0);
            }
            const int j = nt * 16 + l15;
#pragma unroll
            for (int r = 0; r < 4; ++r) {
                int i = w * 16 + l4 * 4 + r;
                if (j < i) Am[i * 64 + j] = -acc[r] * bet[i] * expf(gc[i] - gc[j]);
            }
        }
    }
    uint4 vreg[4];
    {
        const int c = t & 63, db = t >> 6;
#pragma unroll
        for (int r = 0; r < 4; ++r) {
            uint4 kv = *(const uint4*)(sK + c * 128 + ((((4 * db + r) ^ (c & 7))) << 3));
            const u16* kp = (const u16*)&kv;
#pragma unroll
            for (int e = 0; e < 8; ++e) {
                int d = (4 * db + r) * 8 + e;
                sKT[d * 64 + ((((c >> 3) ^ (d & 7))) << 3) + (c & 7)] = kp[e];
            }
            vreg[r] = *(const uint4*)(sVQ + c * 128 + ((((4 * db + r) ^ (c & 7))) << 3));
        }
    }
    __syncthreads();

    {
        const int c = t & 63, db = t >> 6;
#pragma unroll
        for (int r = 0; r < 4; ++r) {
            const u16* vp = (const u16*)&vreg[r];
#pragma unroll
            for (int e = 0; e < 8; ++e) {
                int d = (4 * db + r) * 8 + e;
                sVQ[d * 64 + ((((c >> 3) ^ (d & 7))) << 3) + (c & 7)] = vp[e];
            }
        }
    }
    __syncthreads();

    if (t < 64) {
        float Tc[64];
#pragma unroll
        for (int i = 0; i < 64; ++i) {
            float val = (t == i) ? 1.f : 0.f;
#pragma unroll
            for (int j = 0; j < i; ++j) val = fmaf(Am[i * 64 + j], Tc[j], val);
            Tc[i] = val;
            Am[i * 64 + t] = val;
        }
    }
    __syncthreads();

    float tv[16];
    {
        const int c = t >> 2, j0 = (t & 3) << 4;
#pragma unroll
        for (int q = 0; q < 16; ++q) tv[q] = Am[c * 64 + j0 + q];
    }
    {
        u16* KB = bufK + (size_t)((n << 3) + hs) * 16384;
#pragma unroll
        for (int i = 0; i < 4; ++i) {
            int f = t * 4 + i;
            int d = f >> 3, sb = f & 7;
            uint4 v = *(const uint4*)(sKT + d * 64 + sb * 8);
            if ((h & 1) == 0) *(uint4*)(KB + 8192 + d * 64 + sb * 8) = v;
            int jb = ((sb ^ (d & 7)) << 3);
            float vf[8]; unpack8(v, vf);
#pragma unroll
            for (int e = 0; e < 8; ++e) vf[e] *= bexp[jb + e];
            *(uint4*)(sKT + d * 64 + sb * 8) = pack8(vf);
        }
    }
    __syncthreads();

    {
        u16* Tb = (u16*)Am;
        const int c = t >> 2, j0 = (t & 3) << 4;
        uint4 p0 = pack8(tv), p1 = pack8(tv + 8);
        *(uint4*)(Tb + c * 64 + ((((j0 >> 3) ^ (c & 7))) << 3)) = p0;
        *(uint4*)(Tb + c * 64 + (((((j0 >> 3) + 1) ^ (c & 7))) << 3)) = p1;
    }
    __syncthreads();

    {
        const u16* Tb = (const u16*)Am;
#pragma unroll
        for (int fr2 = 0; fr2 < 2; ++fr2) {
            const int d = w * 32 + fr2 * 16 + l15;
            s16x8 au[2];
#pragma unroll
            for (int kk = 0; kk < 2; ++kk)
                au[kk] = *(const s16x8*)(sKT + d * 64 + (((kk * 4 + l4) ^ (d & 7)) << 3));
#pragma unroll
            for (int fc = 0; fc < 4; ++fc) {
                const int c = fc * 16 + l15;
                f32x4 acc = (f32x4){0.f, 0.f, 0.f, 0.f};
#pragma unroll
                for (int kk = 0; kk < 2; ++kk) {
                    s16x8 bt = *(const s16x8*)(Tb + c * 64 + (((kk * 4 + l4) ^ (c & 7)) << 3));
                    acc = __builtin_amdgcn_mfma_f32_16x16x32_bf16(au[kk], bt, acc, 0, 0, 0);
                }
                const int d0 = w * 32 + fr2 * 16 + l4 * 4;
                uint2 pr;
                pr.x = (u32)f2bf_rne(-acc[0]) | ((u32)f2bf_rne(-acc[1]) << 16);
                pr.y = (u32)f2bf_rne(-acc[2]) | ((u32)f2bf_rne(-acc[3]) << 16);
                *(uint2*)(BB + 8192 + c * 128 + (((d0 >> 3) ^ (c & 7)) << 3) + (d0 & 7)) = pr;
            }
        }
#pragma unroll
        for (int fc2 = 0; fc2 < 2; ++fc2) {
            const int dv = w * 32 + fc2 * 16 + l15;
            s16x8 bv[2];
#pragma unroll
            for (int kk = 0; kk < 2; ++kk)
                bv[kk] = *(const s16x8*)(sVQ + dv * 64 + (((kk * 4 + l4) ^ (dv & 7)) << 3));
#pragma unroll
            for (int fr = 0; fr < 4; ++fr) {
                const int c = fr * 16 + l15;
                f32x4 acc = (f32x4){0.f, 0.f, 0.f, 0.f};
#pragma unroll
                for (int kk = 0; kk < 2; ++kk) {
                    s16x8 at = *(const s16x8*)(Tb + c * 64 + (((kk * 4 + l4) ^ (c & 7)) << 3));
                    acc = __builtin_amdgcn_mfma_f32_16x16x32_bf16(at, bv[kk], acc, 0, 0, 0);
                }
                const int c0 = fr * 16 + l4 * 4;
                uint2 pr;
                pr.x = (u32)f2bf_rne(acc[0]) | ((u32)f2bf_rne(acc[1]) << 16);
                pr.y = (u32)f2bf_rne(acc[2]) | ((u32)f2bf_rne(acc[3]) << 16);
                *(uint2*)(BB + dv * 64 + c0) = pr;
            }
        }
    }
    __syncthreads();

#pragma unroll
    for (int i = 0; i < 4; ++i) {
        int flat = i * 256 + t;
        int c = flat >> 4, dc = (flat & 15) << 3;
        *(uint4*)(sKT + c * 128 + ((((dc >> 3) ^ (c & 7))) << 3)) =
            *(const uint4*)(qn + (size_t)(s0 + c) * 1024 + hs * 128 + dc);
    }
    __syncthreads();

    {
        const u16* sQ = sKT;
        s16x8 aq[4];
#pragma unroll
        for (int kk = 0; kk < 4; ++kk)
            aq[kk] = *(const s16x8*)(sQ + (w * 16 + l15) * 128 + (((kk * 4 + l4) ^ (l15 & 7)) << 3));
#pragma unroll
        for (int nt = 0; nt < 4; ++nt) {
            f32x4 acc = (f32x4){0.f, 0.f, 0.f, 0.f};
            if (nt <= w) {
#pragma unroll
                for (int kk = 0; kk < 4; ++kk) {
                    s16x8 bk = *(const s16x8*)(sK + (nt * 16 + l15) * 128 + (((kk * 4 + l4) ^ (l15 & 7)) << 3));
                    acc = __builtin_amdgcn_mfma_f32_16x16x32_bf16(aq[kk], bk, acc, 0, 0, 0);
                }
            }
            const int jj = nt * 16 + l15;
#pragma unroll
            for (int r = 0; r < 4; ++r) {
                const int i = w * 16 + l4 * 4 + r;
                float val = 0.f;
                if (nt < w || (nt == w && jj <= i)) val = acc[r] * expf(gc[i] - gc[jj]);
                BB[16384 + i * 64 + (((jj >> 3) ^ (i & 7)) << 3) + (jj & 7)] = f2bf_rne(val);
            }
        }
        if ((h & 1) == 0) {
            u16* KB = bufK + (size_t)((n << 3) + hs) * 16384;
#pragma unroll
            for (int i = 0; i < 4; ++i) {
                int f = i * 256 + t;
                int c = f >> 4, sb = f & 15;
                *(uint4*)(KB + c * 128 + sb * 8) = *(const uint4*)(sQ + c * 128 + sb * 8);
            }
        }
    }
}

// ------------- Pass A: serial state recurrence only, checkpoint S^T per chunk -------------
// stage buf (u16): U 0..8192 | kA 8192..16384 | ekd(64 f32) 16384..16512
#define STGA 16512

__global__ __launch_bounds__(256, 1) void scan_state_kernel(const u16* __restrict__ bufB,
                                                            const u16* __restrict__ bufK,
                                                            const float* __restrict__ ekd_g,
                                                            const float* __restrict__ eg_g,
                                                            u16* __restrict__ sstore) {
    __shared__ __align__(16) u16 sStage[2 * STGA];
    __shared__ __align__(16) u16 sSTb[4][16 * 136];
    __shared__ __align__(16) u16 sVTs[4][16 * 72];

    const int h = blockIdx.x >> 1;
    const int dvh = (blockIdx.x & 1) << 6;
    const int hs = h >> 1;
    const int w = threadIdx.x >> 6;
    const int l = threadIdx.x & 63;
    const int l15 = l & 15, l4 = l >> 4, l7 = l & 7;
    const int dv0 = dvh + (w << 4);

    u16* STb = sSTb[w];
    u16* VTs = sVTs[w];

    for (int i = l; i < 16 * 136; i += 64) STb[i] = 0;

    f32x4 Sreg[8];
#pragma unroll
    for (int i = 0; i < 8; ++i) Sreg[i] = (f32x4){0.f, 0.f, 0.f, 0.f};

    auto stage = [&](int n2, u16* dst) {
        const int b2 = (n2 << 4) + h;
        const u16* sU = bufB + (size_t)b2 * 20480 + 8192 + w * 2048 + l * 8;
        u16* dU = dst + w * 2048;
#pragma unroll
        for (int i = 0; i < 4; ++i) gload_lds16(sU + i * 512, dU + i * 512);
        const u16* sKa = bufK + (size_t)((n2 << 3) + hs) * 16384 + 8192 + w * 2048 + l * 8;
        u16* dK = dst + 8192 + w * 2048;
#pragma unroll
        for (int i = 0; i < 4; ++i) gload_lds16(sKa + i * 512, dK + i * 512);
        if (w == 0) gload_lds4(ekd_g + (b2 << 6) + l, dst + 16384);
    };
    auto loadW = [&](int n2, uint2 (&wr)[4]) {
        const u16* wb = bufB + (size_t)((n2 << 4) + h) * 20480 + (size_t)(dv0 + l15) * 64 + l4 * 4;
#pragma unroll
        for (int mt = 0; mt < 4; ++mt) wr[mt] = *(const uint2*)(wb + mt * 16);
    };

    uint2 wA[4], wB[4];
    float egA, egB;
    stage(0, sStage);
    loadW(0, wA);
    egA = eg_g[h];
    __syncthreads();

    int cur = 0;
    for (int n = 0; n < NCHUNK; ++n) {
        const u16* buf = sStage + cur * STGA;
        if (n + 1 < NCHUNK) {
            stage(n + 1, sStage + (cur ^ 1) * STGA);   // prefetch (in flight across barrier)
            loadW(n + 1, wB);
            egB = eg_g[((n + 1) << 4) + h];
        }
        // checkpoint start-of-chunk-n state -> sstore[n]; wave rows dv0..dv0+15
        if (n > 0) {
            u16* dstg = sstore + ((size_t)(n * 16 + h)) * 16384 + (size_t)dv0 * 128;
#pragma unroll
            for (int i = 0; i < 4; ++i) {
                int idx = l * 4 + i;
                int row = idx >> 4, col = (idx & 15) << 3;
                *(uint4*)(dstg + row * 128 + col) = *(const uint4*)(STb + row * 136 + col);
            }
        }
        const u16* bU = buf;
        const u16* bK = buf + 8192;
        const float* ekd = (const float*)(buf + 16384);

        // state B-frags
        s16x8 bF[4];
#pragma unroll
        for (int kk = 0; kk < 4; ++kk)
            bF[kk] = *(const s16x8*)(STb + l15 * 136 + kk * 32 + l4 * 8);

        // V = W + (-U) @ S
        f32x4 V[4];
#pragma unroll
        for (int mt = 0; mt < 4; ++mt) {
            V[mt][0] = bfraw2f((u16)(wA[mt].x & 0xffffu));
            V[mt][1] = bfraw2f((u16)(wA[mt].x >> 16));
            V[mt][2] = bfraw2f((u16)(wA[mt].y & 0xffffu));
            V[mt][3] = bfraw2f((u16)(wA[mt].y >> 16));
        }
#pragma unroll
        for (int kk = 0; kk < 4; ++kk) {
            const int sw = ((kk * 4 + l4) ^ l7) << 3;
#pragma unroll
            for (int mt = 0; mt < 4; ++mt) {
                s16x8 a = *(const s16x8*)(bU + (mt * 16 + l15) * 128 + sw);
                V[mt] = __builtin_amdgcn_mfma_f32_16x16x32_bf16(a, bF[kk], V[mt], 0, 0, 0);
            }
        }

        // VTs = V^T * ekd[c]
#pragma unroll
        for (int mt = 0; mt < 4; ++mt) {
            const int cb = mt * 16 + l4 * 4;
            uint2 us;
            us.x = (u32)f2bf_rne(V[mt][0] * ekd[cb]) | ((u32)f2bf_rne(V[mt][1] * ekd[cb + 1]) << 16);
            us.y = (u32)f2bf_rne(V[mt][2] * ekd[cb + 2]) | ((u32)f2bf_rne(V[mt][3] * ekd[cb + 3]) << 16);
            *(uint2*)(VTs + l15 * 72 + cb) = us;
        }

        // S = eg*S + kA @ VTs
        s16x8 sF0 = *(const s16x8*)(VTs + l15 * 72 + l4 * 8);
        s16x8 sF1 = *(const s16x8*)(VTs + l15 * 72 + 32 + l4 * 8);
#pragma unroll
        for (int nt = 0; nt < 8; ++nt) {
#pragma unroll
            for (int r = 0; r < 4; ++r) Sreg[nt][r] *= egA;
            s16x8 a0 = *(const s16x8*)(bK + (nt * 16 + l15) * 64 + ((l4 ^ l7) << 3));
            Sreg[nt] = __builtin_amdgcn_mfma_f32_16x16x32_bf16(a0, sF0, Sreg[nt], 0, 0, 0);
            s16x8 a1 = *(const s16x8*)(bK + (nt * 16 + l15) * 64 + (((4 + l4) ^ l7) << 3));
            Sreg[nt] = __builtin_amdgcn_mfma_f32_16x16x32_bf16(a1, sF1, Sreg[nt], 0, 0, 0);
        }
        // bf16 mirror
#pragma unroll
        for (int nt = 0; nt < 8; ++nt) {
            uint2 sv;
            sv.x = (u32)f2bf_rne(Sreg[nt][0]) | ((u32)f2bf_rne(Sreg[nt][1]) << 16);
            sv.y = (u32)f2bf_rne(Sreg[nt][2]) | ((u32)f2bf_rne(Sreg[nt][3]) << 16);
            *(uint2*)(STb + l15 * 136 + nt * 16 + l4 * 4) = sv;
        }
        __syncthreads();
#pragma unroll
        for (int i = 0; i < 4; ++i) wA[i] = wB[i];
        egA = egB;
        cur ^= 1;
    }
}

// ------------- Pass B: parallel output computation (recompute V, O) -------------
// sStage (u16): U 0..8192 | Aqk 8192..12288 | qA 12288..20480 | egc(64 f32) 20480..20608
__global__ __launch_bounds__(512, 4) void scan_out_kernel(const u16* __restrict__ bufB,
                                                          const u16* __restrict__ bufK,
                                                          const u16* __restrict__ sstore,
                                                          const float* __restrict__ egc_g,
                                                          u16* __restrict__ o) {
    __shared__ __align__(16) u16 sStage[20608];
    __shared__ __align__(16) u16 sVT[8][16 * 72];

    const int bb = blockIdx.x;             // n*16 + h
    const int n = bb >> 4, h = bb & 15, hs = h >> 1;
    const int t = threadIdx.x;
    const int w = t >> 6, l = t & 63;
    const int l15 = l & 15, l4 = l >> 4, l7 = l & 7;
    const int dv0 = w << 4;
    u16* VT = sVT[w];

    // stage U+Aqk (24KB) and qA (16KB): 40 chunks of 1024B, 5 per wave
#pragma unroll
    for (int i = 0; i < 5; ++i) {
        int c = w + i * 8;
        if (c < 24)
            gload_lds16(bufB + (size_t)bb * 20480 + 8192 + c * 512 + l * 8, sStage + c * 512);
        else
            gload_lds16(bufK + (size_t)((n << 3) + hs) * 16384 + (c - 24) * 512 + l * 8,
                        sStage + 12288 + (c - 24) * 512);
    }
    if (w == 0) gload_lds4(egc_g + (bb << 6) + l, sStage + 20480);

    // W frags + state B-frags (direct from global)
    uint2 wr[4];
    {
        const u16* wb = bufB + (size_t)bb * 20480 + (size_t)(dv0 + l15) * 64 + l4 * 4;
#pragma unroll
        for (int mt = 0; mt < 4; ++mt) wr[mt] = *(const uint2*)(wb + mt * 16);
    }
    s16x8 bF[4];
    if (n > 0) {
        const u16* sp = sstore + (size_t)bb * 16384 + (size_t)(dv0 + l15) * 128 + l4 * 8;
#pragma unroll
        for (int kk = 0; kk < 4; ++kk)
            bF[kk] = *(const s16x8*)(sp + kk * 32);
    }
    __syncthreads();

    const u16* bU = sStage;
    const u16* bA = sStage + 8192;
    const u16* qA = sStage + 12288;
    const float* egc = (const float*)(sStage + 20480);

    // V = W + (-U) @ S
    f32x4 V[4];
#pragma unroll
    for (int mt = 0; mt < 4; ++mt) {
        V[mt][0] = bfraw2f((u16)(wr[mt].x & 0xffffu));
        V[mt][1] = bfraw2f((u16)(wr[mt].x >> 16));
        V[mt][2] = bfraw2f((u16)(wr[mt].y & 0xffffu));
        V[mt][3] = bfraw2f((u16)(wr[mt].y >> 16));
    }
    f32x4 O[4];
#pragma unroll
    for (int mt = 0; mt < 4; ++mt) O[mt] = (f32x4){0.f, 0.f, 0.f, 0.f};
    if (n > 0) {
#pragma unroll
        for (int kk = 0; kk < 4; ++kk) {
            const int sw = ((kk * 4 + l4) ^ l7) << 3;
#pragma unroll
            for (int mt = 0; mt < 4; ++mt) {
                s16x8 a = *(const s16x8*)(bU + (mt * 16 + l15) * 128 + sw);
                V[mt] = __builtin_amdgcn_mfma_f32_16x16x32_bf16(a, bF[kk], V[mt], 0, 0, 0);
            }
        }
        // O = egc * (Q @ S)
#pragma unroll
        for (int kk = 0; kk < 4; ++kk) {
            const int sw = ((kk * 4 + l4) ^ l7) << 3;
#pragma unroll
            for (int mt = 0; mt < 4; ++mt) {
                s16x8 a = *(const s16x8*)(qA + (mt * 16 + l15) * 128 + sw);
                O[mt] = __builtin_amdgcn_mfma_f32_16x16x32_bf16(a, bF[kk], O[mt], 0, 0, 0);
            }
        }
#pragma unroll
        for (int mt = 0; mt < 4; ++mt)
#pragma unroll
            for (int r = 0; r < 4; ++r) O[mt][r] *= egc[mt * 16 + l4 * 4 + r];
    }

    // V -> VT (wave-private)
#pragma unroll
    for (int mt = 0; mt < 4; ++mt) {
        const int cb = mt * 16 + l4 * 4;
        uint2 uv;
        uv.x = (u32)f2bf_rne(V[mt][0]) | ((u32)f2bf_rne(V[mt][1]) << 16);
        uv.y = (u32)f2bf_rne(V[mt][2]) | ((u32)f2bf_rne(V[mt][3]) << 16);
        *(uint2*)(VT + l15 * 72 + cb) = uv;
    }
    // O += Aqk @ V
    s16x8 vF0 = *(const s16x8*)(VT + l15 * 72 + l4 * 8);
    s16x8 vF1 = *(const s16x8*)(VT + l15 * 72 + 32 + l4 * 8);
#pragma unroll
    for (int mt = 0; mt < 4; ++mt) {
        s16x8 a = *(const s16x8*)(bA + (mt * 16 + l15) * 64 + ((l4 ^ l7) << 3));
        O[mt] = __builtin_amdgcn_mfma_f32_16x16x32_bf16(a, vF0, O[mt], 0, 0, 0);
    }
#pragma unroll
    for (int mt = 0; mt < 4; ++mt) {
        s16x8 a = *(const s16x8*)(bA + (mt * 16 + l15) * 64 + (((4 + l4) ^ l7) << 3));
        O[mt] = __builtin_amdgcn_mfma_f32_16x16x32_bf16(a, vF1, O[mt], 0, 0, 0);
    }

    const int s0 = n << 6;
#pragma unroll
    for (int mt = 0; mt < 4; ++mt)
#pragma unroll
        for (int r = 0; r < 4; ++r)
            o[(size_t)(s0 + mt * 16 + l4 * 4 + r) * 2048 + (h << 7) + dv0 + l15] = f2bf_rne(O[mt][r]);
}

// ------------- gated rmsnorm * silu(z) -> bf16 -------------
__global__ __launch_bounds__(256) void gate_kernel(const u16* __restrict__ o,
                                                   const u16* __restrict__ Cz,
                                                   const float* __restrict__ norm_w,
                                                   u16* __restrict__ gated) {
    const int s = blockIdx.x, t = threadIdx.x;
    const int c8 = t << 3, hh = t >> 4;
    __shared__ float ssq[16];
    if (t < 16) ssq[t] = 0.f;
    float ov[8];
    unpack8(*(const uint4*)(o + (size_t)s * 2048 + c8), ov);
    float p = 0.f;
#pragma unroll
    for (int i = 0; i < 8; ++i) p += ov[i] * ov[i];
    __syncthreads();
    atomicAdd(&ssq[hh], p);
    __syncthreads();
    const float rms = rsqrtf(ssq[hh] * 0.0078125f + EPSF);
    float zf[8];
    unpack8(*(const uint4*)(Cz + (size_t)s * 2048 + c8), zf);
    const int d0 = c8 & 127;
    float res[8];
#pragma unroll
    for (int i = 0; i < 8; ++i) {
        float z = zf[i];
        float sz = z / (1.f + expf(-z));
        res[i] = ov[i] * rms * norm_w[d0 + i] * sz;
    }
    *(uint4*)(gated + (size_t)s * 2048 + c8) = pack8(res);
}

extern "C" void kernel_launch(void* const* d_in, const int* in_sizes, int n_in,
                              void* d_out, int out_size, void* d_ws, size_t ws_size,
                              hipStream_t stream) {
    (void)in_sizes; (void)n_in; (void)out_size; (void)ws_size;
    const float* x       = (const float*)d_in[0];
    const float* W_qkv   = (const float*)d_in[1];
    const float* W_z     = (const float*)d_in[2];
    const float* W_b     = (const float*)d_in[3];
    const float* W_a     = (const float*)d_in[4];
    const float* conv_w  = (const float*)d_in[5];
    const float* A_log   = (const float*)d_in[6];
    const float* dt_bias = (const float*)d_in[7];
    const float* norm_w  = (const float*)d_in[8];
    const float* W_out   = (const float*)d_in[9];

    char* p = (char*)d_ws;
    auto alloc = [&](size_t bytes) {
        char* r = p;
        p += (bytes + 255) & ~(size_t)255;
        return r;
    };
    u16* Cmix    = (u16*)alloc((size_t)S_LEN * NQKV * 2);       // 67.1 MB (dead after prep)
    char* extra  = alloc((size_t)50331648); (void)extra;        // 50.3 MB (bufB/bufK tail)
    u16* qn      = (u16*)alloc((size_t)S_LEN * HKN * DKD * 2);  // 16.8 MB
    u16* kn      = (u16*)alloc((size_t)S_LEN * HKN * DKD * 2);  // 16.8 MB
    u16* vb      = (u16*)alloc((size_t)S_LEN * HVN * DVD * 2);  // 33.5 MB
    float* egc   = (float*)alloc((size_t)NCHUNK * HVN * CLEN * 4);
    float* ekd   = (float*)alloc((size_t)NCHUNK * HVN * CLEN * 4);
    float* eg    = (float*)alloc((size_t)NCHUNK * HVN * 4);
    float* beta  = (float*)alloc((size_t)S_LEN * HVN * 4);
    float* g     = (float*)alloc((size_t)S_LEN * HVN * 4);
    // lifetime-disjoint overlays:
    u16* bufB  = Cmix;
    u16* bufK  = (u16*)((char*)Cmix + (size_t)83886080);
    u16* o_buf = qn;
    u16* Cz    = vb;
    u16* gated = Cmix;
    // scratch inside d_out (dead before final GEMM writes d_out):
    u16* xbf    = (u16*)d_out;
    u16* Wq_t   = (u16*)d_out + (size_t)16777216;
    u16* Wz_t   = (u16*)d_out + (size_t)25165824;
    u16* sstore = (u16*)d_out;                       // 2048 x 16384 u16 = 67.1 MB (exact fit)
    u16* Wout_t = qn;

    ba_kernel<<<S_LEN / 8, 256, 0, stream>>>(x, W_b, W_a, A_log, dt_bias, beta, g);
    cvt_x_kernel<<<S_LEN * HID / (256 * 8), 256, 0, stream>>>(x, xbf);
    cvt_wT_kernel<<<dim3(NQKV / 64, HID / 64), 256, 0, stream>>>(W_qkv, Wq_t, NQKV, HID);
    cvt_wT_kernel<<<dim3(HID / 64, HID / 64), 256, 0, stream>>>(W_z, Wz_t, HID, HID);
    gemm_bt<0><<<dim3(NQKV / 128, S_LEN / 128), 256, 0, stream>>>(xbf, Wq_t, Cmix, S_LEN, NQKV, HID);
    prep_kernel<<<S_LEN, 512, 0, stream>>>(Cmix, conv_w, beta, qn, kn, vb);
    precomp_kernel<<<NCHUNK * HVN, 256, 0, stream>>>(qn, kn, vb, g, beta, bufB, bufK, egc, ekd, eg);
    gemm_bt<0><<<dim3(HID / 128, S_LEN / 128), 256, 0, stream>>>(xbf, Wz_t, Cz, S_LEN, HID, HID);
    // Pass A: serial recurrence + checkpoints (sstore over dead xbf/Wq_t/Wz_t in d_out)
    scan_state_kernel<<<HVN * 2, 256, 0, stream>>>(bufB, bufK, ekd, eg, sstore);
    // Pass B: parallel output computation
    scan_out_kernel<<<NCHUNK * HVN, 512, 0, stream>>>(bufB, bufK, sstore, egc, o_buf);
    gate_kernel<<<S_LEN, 256, 0, stream>>>(o_buf, Cz, norm_w, gated);
    cvt_wT_kernel<<<dim3(HID / 64, HID / 64), 256, 0, stream>>>(W_out, Wout_t, HID, HID);
    gemm_bt<1><<<dim3(HID / 128, S_LEN / 128), 256, 0, stream>>>(gated, Wout_t, d_out, S_LEN, HID, HID);
}

// Round 6
// 1225.311 us; speedup vs baseline: 3.4350x; 1.0017x over previous
//
#include <hip/hip_runtime.h>

#define S_LEN 8192
#define HID 2048
#define HKN 8
#define HVN 16
#define DKD 128
#define DVD 128
#define NCHUNK 128
#define CLEN 64
#define NQKV 4096
#define EPSF 1e-6f

typedef unsigned int u32;
typedef unsigned short u16;
typedef __attribute__((ext_vector_type(8))) short s16x8;
typedef __attribute__((ext_vector_type(4))) float f32x4;

__device__ __forceinline__ float bfraw2f(u16 v) { return __uint_as_float(((u32)v) << 16); }
__device__ __forceinline__ u16 f2bf_rne(float f) {
    u32 u = __float_as_uint(f);
    u32 r = u + 0x7fffu + ((u >> 16) & 1u);
    return (u16)(r >> 16);
}
// packed RNE f32x2 -> bf16x2 (same rounding as f2bf_rne, 1 instruction)
__device__ __forceinline__ u32 pk_bf16(float lo, float hi) {
    u32 r;
    asm("v_cvt_pk_bf16_f32 %0, %1, %2" : "=v"(r) : "v"(lo), "v"(hi));
    return r;
}
__device__ __forceinline__ void unpack8(uint4 u, float* f) {
    const u32 a[4] = {u.x, u.y, u.z, u.w};
#pragma unroll
    for (int q = 0; q < 4; ++q) {
        f[2*q]   = __uint_as_float(a[q] << 16);
        f[2*q+1] = __uint_as_float(a[q] & 0xffff0000u);
    }
}
__device__ __forceinline__ uint4 pack8(const float* v) {
    uint4 r;
    r.x = (u32)f2bf_rne(v[0]) | ((u32)f2bf_rne(v[1]) << 16);
    r.y = (u32)f2bf_rne(v[2]) | ((u32)f2bf_rne(v[3]) << 16);
    r.z = (u32)f2bf_rne(v[4]) | ((u32)f2bf_rne(v[5]) << 16);
    r.w = (u32)f2bf_rne(v[6]) | ((u32)f2bf_rne(v[7]) << 16);
    return r;
}

// async global->LDS staging (lane-strided 16B; LDS dest wave-uniform base + lane*16)
__device__ __forceinline__ void gload_lds16(const u16* g, u16* l) {
    __builtin_amdgcn_global_load_lds((const __attribute__((address_space(1))) unsigned int*)g,
                                     (__attribute__((address_space(3))) unsigned int*)l, 16, 0, 0);
}
__device__ __forceinline__ void gload_lds4(const float* g, u16* l) {
    __builtin_amdgcn_global_load_lds((const __attribute__((address_space(1))) unsigned int*)g,
                                     (__attribute__((address_space(3))) unsigned int*)l, 4, 0, 0);
}

// ------------- b,a projections (scalar, broadcast-x) + activations -------------
__global__ __launch_bounds__(256) void ba_kernel(const float* __restrict__ x,
                                                 const float* __restrict__ Wb,
                                                 const float* __restrict__ Wa,
                                                 const float* __restrict__ A_log,
                                                 const float* __restrict__ dt_bias,
                                                 float* __restrict__ beta,
                                                 float* __restrict__ g) {
    const int t = threadIdx.x;
    const int row = blockIdx.x * 8 + (t >> 5);
    const int c = t & 31;
    const int cc = c & 15;
    const float* W = (c < 16) ? Wb : Wa;
    const float* xr = x + (size_t)row * HID;
    float acc = 0.f;
    for (int k = 0; k < HID; ++k) acc = fmaf(xr[k], W[k * 16 + cc], acc);
    if (c < 16) {
        beta[row * 16 + cc] = 1.f / (1.f + expf(-acc));
    } else {
        float v = acc + dt_bias[cc];
        float sp = (v > 20.f) ? v : log1pf(expf(v));
        g[row * 16 + cc] = -expf(A_log[cc]) * sp;
    }
}

// ------------- fp32 -> bf16 bulk convert -------------
__global__ __launch_bounds__(256) void cvt_x_kernel(const float* __restrict__ x,
                                                    u16* __restrict__ xb) {
    const size_t i8 = ((size_t)blockIdx.x * 256 + threadIdx.x) << 3;
    float4 a = *(const float4*)(x + i8);
    float4 b = *(const float4*)(x + i8 + 4);
    float v[8] = {a.x, a.y, a.z, a.w, b.x, b.y, b.z, b.w};
    *(uint4*)(xb + i8) = pack8(v);
}

// ------------- W [K,N] fp32 -> Wt [N,K] bf16 (tiled transpose) -------------
__global__ __launch_bounds__(256) void cvt_wT_kernel(const float* __restrict__ W,
                                                     u16* __restrict__ Wt,
                                                     int N, int K) {
    __shared__ u16 T[64 * 72];
    const int t = threadIdx.x;
    const int n0 = blockIdx.x * 64;
    const int k0 = blockIdx.y * 64;
#pragma unroll
    for (int i = 0; i < 4; ++i) {
        int flat = i * 256 + t;
        int kr = flat >> 4, c4 = (flat & 15) << 2;
        float4 v = *(const float4*)(W + (size_t)(k0 + kr) * N + n0 + c4);
        T[(c4 + 0) * 72 + kr] = f2bf_rne(v.x);
        T[(c4 + 1) * 72 + kr] = f2bf_rne(v.y);
        T[(c4 + 2) * 72 + kr] = f2bf_rne(v.z);
        T[(c4 + 3) * 72 + kr] = f2bf_rne(v.w);
    }
    __syncthreads();
#pragma unroll
    for (int i = 0; i < 2; ++i) {
        int flat = i * 256 + t;
        int n = flat >> 3, k8 = (flat & 7) << 3;
        *(uint4*)(Wt + (size_t)(n0 + n) * K + k0 + k8) = *(const uint4*)(T + n * 72 + k8);
    }
}

// ------------- MFMA GEMM (m97 structure + XCD swizzle): C = A * Bt^T -------------
template <int F32OUT>
__global__ __launch_bounds__(256) void gemm_bt(const u16* __restrict__ A,
                                               const u16* __restrict__ Bt,
                                               void* __restrict__ Cv,
                                               int M, int N, int K) {
    __shared__ __align__(16) u16 As[128 * 64];
    __shared__ __align__(16) u16 Bs[128 * 64];
    const int t = threadIdx.x;
    const int nwg = gridDim.x * gridDim.y;
    int bid = blockIdx.y * gridDim.x + blockIdx.x;
    bid = (bid & 7) * (nwg >> 3) + (bid >> 3);
    const int n0 = (bid % gridDim.x) * 128;
    const int m0 = (bid / gridDim.x) * 128;
    const int w = t >> 6, lane = t & 63;
    const int wm = (w >> 1) * 64, wn = (w & 1) * 64;
    const int ml = lane & 15, kq = lane >> 4;
    f32x4 acc[4][4];
#pragma unroll
    for (int i = 0; i < 4; ++i)
#pragma unroll
        for (int j = 0; j < 4; ++j) acc[i][j] = (f32x4){0.f, 0.f, 0.f, 0.f};

    for (int k0 = 0; k0 < K; k0 += 64) {
#pragma unroll
        for (int r = 0; r < 4; ++r) {
            int flat = r * 256 + t;
            int row = flat >> 3, kc = (flat & 7) << 3;
            gload_lds16(A  + (size_t)(m0 + row) * K + k0 + kc, As + flat * 8);
            gload_lds16(Bt + (size_t)(n0 + row) * K + k0 + kc, Bs + flat * 8);
        }
        __syncthreads();
#pragma unroll
        for (int ks = 0; ks < 2; ++ks) {
            s16x8 af[4], bfr[4];
#pragma unroll
            for (int mt = 0; mt < 4; ++mt)
                af[mt] = *(const s16x8*)(As + (wm + mt * 16 + ml) * 64 + ks * 32 + kq * 8);
#pragma unroll
            for (int nt = 0; nt < 4; ++nt)
                bfr[nt] = *(const s16x8*)(Bs + (wn + nt * 16 + ml) * 64 + ks * 32 + kq * 8);
#pragma unroll
            for (int mt = 0; mt < 4; ++mt)
#pragma unroll
                for (int nt = 0; nt < 4; ++nt)
                    acc[mt][nt] = __builtin_amdgcn_mfma_f32_16x16x32_bf16(af[mt], bfr[nt], acc[mt][nt], 0, 0, 0);
        }
        __syncthreads();
    }
#pragma unroll
    for (int mt = 0; mt < 4; ++mt)
#pragma unroll
        for (int nt = 0; nt < 4; ++nt)
#pragma unroll
            for (int r = 0; r < 4; ++r) {
                int row = m0 + wm + mt * 16 + kq * 4 + r;
                int col = n0 + wn + nt * 16 + ml;
                float v = acc[mt][nt][r];
                if (F32OUT)
                    ((float*)Cv)[(size_t)row * N + col] = v;
                else
                    ((u16*)Cv)[(size_t)row * N + col] = f2bf_rne(v);
            }
}

// ------------- conv(K=4) + silu + l2norm + beta-fold prep -------------
__global__ __launch_bounds__(512) void prep_kernel(const u16* __restrict__ Cmix,
                                                   const float* __restrict__ conv_w,
                                                   const float* __restrict__ beta,
                                                   u16* __restrict__ qn,
                                                   u16* __restrict__ kn,
                                                   u16* __restrict__ vb) {
    const int s = blockIdx.x;
    const int t = threadIdx.x;
    const int c8 = t << 3;
    __shared__ float ssq[16];
    if (t < 16) ssq[t] = 0.f;

    float y[8];
#pragma unroll
    for (int i = 0; i < 8; ++i) y[i] = 0.f;
    {
        uint4 mrow[4];
#pragma unroll
        for (int j = 0; j < 4; ++j) {
            int r = s - 3 + j;
            if (r >= 0) mrow[j] = *(const uint4*)(Cmix + (size_t)r * NQKV + c8);
            else        mrow[j] = uint4{0u, 0u, 0u, 0u};
        }
        float cw[8][4];
#pragma unroll
        for (int i = 0; i < 8; ++i) {
            float4 cv = *(const float4*)(conv_w + (size_t)(c8 + i) * 4);
            cw[i][0] = cv.x; cw[i][1] = cv.y; cw[i][2] = cv.z; cw[i][3] = cv.w;
        }
#pragma unroll
        for (int j = 0; j < 4; ++j) {
            float mf[8];
            unpack8(mrow[j], mf);
#pragma unroll
            for (int i = 0; i < 8; ++i) y[i] = fmaf(mf[i], cw[i][j], y[i]);
        }
#pragma unroll
        for (int i = 0; i < 8; ++i) {
            float v = y[i];
            y[i] = v / (1.f + expf(-v));
        }
    }
    __syncthreads();
    if (t < 256) {
        float p = 0.f;
#pragma unroll
        for (int i = 0; i < 8; ++i) p += y[i] * y[i];
        atomicAdd(&ssq[t >> 4], p);
    }
    __syncthreads();
    if (t < 128) {
        float rn = rsqrtf(ssq[t >> 4] + EPSF) * 0.08838834764831845f;
        float ov[8];
#pragma unroll
        for (int i = 0; i < 8; ++i) ov[i] = y[i] * rn;
        *(uint4*)(qn + (size_t)s * 1024 + c8) = pack8(ov);
    } else if (t < 256) {
        float rn = rsqrtf(ssq[t >> 4] + EPSF);
        float ov[8];
#pragma unroll
        for (int i = 0; i < 8; ++i) ov[i] = y[i] * rn;
        *(uint4*)(kn + (size_t)s * 1024 + (c8 - 1024)) = pack8(ov);
    } else {
        int vh = (c8 - 2048) >> 7;
        float bb = beta[s * 16 + vh];
        float ov[8];
#pragma unroll
        for (int i = 0; i < 8; ++i) ov[i] = y[i] * bb;
        *(uint4*)(vb + (size_t)s * 2048 + (c8 - 2048)) = pack8(ov);
    }
}

// ------------- per-(chunk,head) precompute — MFMA version -------------
// bufB per b (20480 u16): [ W[dv][c] 8192 | U(-u)[c][dk] swz 8192 | Aqk[i][j] swz 4096 ]
// bufK per bk=n*8+hs (16384 u16): [ qA[c][dk] swz 8192 | kA[dk][c] swz 8192 ]
__global__ __launch_bounds__(256, 2) void precomp_kernel(const u16* __restrict__ qn,
                                                         const u16* __restrict__ kn,
                                                         const u16* __restrict__ vb,
                                                         const float* __restrict__ g,
                                                         const float* __restrict__ beta,
                                                         u16* __restrict__ bufB,
                                                         u16* __restrict__ bufK,
                                                         float* __restrict__ egc_arr,
                                                         float* __restrict__ ekd_arr,
                                                         float* __restrict__ eg) {
    const int b = blockIdx.x;  // n*16 + h
    const int n = b >> 4, h = b & 15, hs = h >> 1;
    const int t = threadIdx.x;
    const int s0 = n * 64;
    u16* BB = bufB + (size_t)b * 20480;

    __shared__ __align__(16) u16 sK[64 * 128];
    __shared__ __align__(16) u16 sVQ[64 * 128];
    __shared__ __align__(16) u16 sKT[64 * 128];
    __shared__ __align__(16) float Am[64 * 64];
    __shared__ float gc[64], bet[64], bexp[64];

    const int w = t >> 6, l = t & 63;
    const int l15 = l & 15, l4 = l >> 4;

#pragma unroll
    for (int i = 0; i < 4; ++i) {
        int flat = i * 256 + t;
        int c = flat >> 4, dc = (flat & 15) << 3;
        int sw = c * 128 + ((((dc >> 3) ^ (c & 7))) << 3);
        *(uint4*)(sK + sw)  = *(const uint4*)(kn + (size_t)(s0 + c) * 1024 + hs * 128 + dc);
        *(uint4*)(sVQ + sw) = *(const uint4*)(vb + (size_t)(s0 + c) * 2048 + h * 128 + dc);
    }
    if (t < 64) {
        gc[t] = g[(size_t)(s0 + t) * 16 + h];
        bet[t] = beta[(size_t)(s0 + t) * 16 + h];
    }
    __syncthreads();
    if (t == 0) {
        float run = 0.f;
        for (int c = 0; c < 64; ++c) { run += gc[c]; gc[c] = run; }
    }
    __syncthreads();
    if (t < 64) {
        float e = expf(gc[t]);
        float ek = expf(gc[63] - gc[t]);
        bexp[t] = bet[t] * e;
        egc_arr[b * 64 + t] = e;
        ekd_arr[b * 64 + t] = ek;
    }
    if (t == 0) eg[b] = expf(gc[63]);
    __syncthreads();

    {
        s16x8 ak[4];
#pragma unroll
        for (int kk = 0; kk < 4; ++kk)
            ak[kk] = *(const s16x8*)(sK + (w * 16 + l15) * 128 + (((kk * 4 + l4) ^ (l15 & 7)) << 3));
        for (int nt = 0; nt <= w; ++nt) {
            f32x4 acc = (f32x4){0.f, 0.f, 0.f, 0.f};
#pragma unroll
            for (int kk = 0; kk < 4; ++kk) {
                s16x8 bk = *(const s16x8*)(sK + (nt * 16 + l15) * 128 + (((kk * 4 + l4) ^ (l15 & 7)) << 3));
                acc = __builtin_amdgcn_mfma_f32_16x16x32_bf16(ak[kk], bk, acc, 0, 0, 0);
            }
            const int j = nt * 16 + l15;
#pragma unroll
            for (int r = 0; r < 4; ++r) {
                int i = w * 16 + l4 * 4 + r;
                if (j < i) Am[i * 64 + j] = -acc[r] * bet[i] * expf(gc[i] - gc[j]);
            }
        }
    }
    uint4 vreg[4];
    {
        const int c = t & 63, db = t >> 6;
#pragma unroll
        for (int r = 0; r < 4; ++r) {
            uint4 kv = *(const uint4*)(sK + c * 128 + ((((4 * db + r) ^ (c & 7))) << 3));
            const u16* kp = (const u16*)&kv;
#pragma unroll
            for (int e = 0; e < 8; ++e) {
                int d = (4 * db + r) * 8 + e;
                sKT[d * 64 + ((((c >> 3) ^ (d & 7))) << 3) + (c & 7)] = kp[e];
            }
            vreg[r] = *(const uint4*)(sVQ + c * 128 + ((((4 * db + r) ^ (c & 7))) << 3));
        }
    }
    __syncthreads();

    {
        const int c = t & 63, db = t >> 6;
#pragma unroll
        for (int r = 0; r < 4; ++r) {
            const u16* vp = (const u16*)&vreg[r];
#pragma unroll
            for (int e = 0; e < 8; ++e) {
                int d = (4 * db + r) * 8 + e;
                sVQ[d * 64 + ((((c >> 3) ^ (d & 7))) << 3) + (c & 7)] = vp[e];
            }
        }
    }
    __syncthreads();

    if (t < 64) {
        float Tc[64];
#pragma unroll
        for (int i = 0; i < 64; ++i) {
            float val = (t == i) ? 1.f : 0.f;
#pragma unroll
            for (int j = 0; j < i; ++j) val = fmaf(Am[i * 64 + j], Tc[j], val);
            Tc[i] = val;
            Am[i * 64 + t] = val;
        }
    }
    __syncthreads();

    float tv[16];
    {
        const int c = t >> 2, j0 = (t & 3) << 4;
#pragma unroll
        for (int q = 0; q < 16; ++q) tv[q] = Am[c * 64 + j0 + q];
    }
    {
        u16* KB = bufK + (size_t)((n << 3) + hs) * 16384;
#pragma unroll
        for (int i = 0; i < 4; ++i) {
            int f = t * 4 + i;
            int d = f >> 3, sb = f & 7;
            uint4 v = *(const uint4*)(sKT + d * 64 + sb * 8);
            if ((h & 1) == 0) *(uint4*)(KB + 8192 + d * 64 + sb * 8) = v;
            int jb = ((sb ^ (d & 7)) << 3);
            float vf[8]; unpack8(v, vf);
#pragma unroll
            for (int e = 0; e < 8; ++e) vf[e] *= bexp[jb + e];
            *(uint4*)(sKT + d * 64 + sb * 8) = pack8(vf);
        }
    }
    __syncthreads();

    {
        u16* Tb = (u16*)Am;
        const int c = t >> 2, j0 = (t & 3) << 4;
        uint4 p0 = pack8(tv), p1 = pack8(tv + 8);
        *(uint4*)(Tb + c * 64 + ((((j0 >> 3) ^ (c & 7))) << 3)) = p0;
        *(uint4*)(Tb + c * 64 + (((((j0 >> 3) + 1) ^ (c & 7))) << 3)) = p1;
    }
    __syncthreads();

    {
        const u16* Tb = (const u16*)Am;
#pragma unroll
        for (int fr2 = 0; fr2 < 2; ++fr2) {
            const int d = w * 32 + fr2 * 16 + l15;
            s16x8 au[2];
#pragma unroll
            for (int kk = 0; kk < 2; ++kk)
                au[kk] = *(const s16x8*)(sKT + d * 64 + (((kk * 4 + l4) ^ (d & 7)) << 3));
#pragma unroll
            for (int fc = 0; fc < 4; ++fc) {
                const int c = fc * 16 + l15;
                f32x4 acc = (f32x4){0.f, 0.f, 0.f, 0.f};
#pragma unroll
                for (int kk = 0; kk < 2; ++kk) {
                    s16x8 bt = *(const s16x8*)(Tb + c * 64 + (((kk * 4 + l4) ^ (c & 7)) << 3));
                    acc = __builtin_amdgcn_mfma_f32_16x16x32_bf16(au[kk], bt, acc, 0, 0, 0);
                }
                const int d0 = w * 32 + fr2 * 16 + l4 * 4;
                uint2 pr;
                pr.x = (u32)f2bf_rne(-acc[0]) | ((u32)f2bf_rne(-acc[1]) << 16);
                pr.y = (u32)f2bf_rne(-acc[2]) | ((u32)f2bf_rne(-acc[3]) << 16);
                *(uint2*)(BB + 8192 + c * 128 + (((d0 >> 3) ^ (c & 7)) << 3) + (d0 & 7)) = pr;
            }
        }
#pragma unroll
        for (int fc2 = 0; fc2 < 2; ++fc2) {
            const int dv = w * 32 + fc2 * 16 + l15;
            s16x8 bv[2];
#pragma unroll
            for (int kk = 0; kk < 2; ++kk)
                bv[kk] = *(const s16x8*)(sVQ + dv * 64 + (((kk * 4 + l4) ^ (dv & 7)) << 3));
#pragma unroll
            for (int fr = 0; fr < 4; ++fr) {
                const int c = fr * 16 + l15;
                f32x4 acc = (f32x4){0.f, 0.f, 0.f, 0.f};
#pragma unroll
                for (int kk = 0; kk < 2; ++kk) {
                    s16x8 at = *(const s16x8*)(Tb + c * 64 + (((kk * 4 + l4) ^ (c & 7)) << 3));
                    acc = __builtin_amdgcn_mfma_f32_16x16x32_bf16(at, bv[kk], acc, 0, 0, 0);
                }
                const int c0 = fr * 16 + l4 * 4;
                uint2 pr;
                pr.x = (u32)f2bf_rne(acc[0]) | ((u32)f2bf_rne(acc[1]) << 16);
                pr.y = (u32)f2bf_rne(acc[2]) | ((u32)f2bf_rne(acc[3]) << 16);
                *(uint2*)(BB + dv * 64 + c0) = pr;
            }
        }
    }
    __syncthreads();

#pragma unroll
    for (int i = 0; i < 4; ++i) {
        int flat = i * 256 + t;
        int c = flat >> 4, dc = (flat & 15) << 3;
        *(uint4*)(sKT + c * 128 + ((((dc >> 3) ^ (c & 7))) << 3)) =
            *(const uint4*)(qn + (size_t)(s0 + c) * 1024 + hs * 128 + dc);
    }
    __syncthreads();

    {
        const u16* sQ = sKT;
        s16x8 aq[4];
#pragma unroll
        for (int kk = 0; kk < 4; ++kk)
            aq[kk] = *(const s16x8*)(sQ + (w * 16 + l15) * 128 + (((kk * 4 + l4) ^ (l15 & 7)) << 3));
#pragma unroll
        for (int nt = 0; nt < 4; ++nt) {
            f32x4 acc = (f32x4){0.f, 0.f, 0.f, 0.f};
            if (nt <= w) {
#pragma unroll
                for (int kk = 0; kk < 4; ++kk) {
                    s16x8 bk = *(const s16x8*)(sK + (nt * 16 + l15) * 128 + (((kk * 4 + l4) ^ (l15 & 7)) << 3));
                    acc = __builtin_amdgcn_mfma_f32_16x16x32_bf16(aq[kk], bk, acc, 0, 0, 0);
                }
            }
            const int jj = nt * 16 + l15;
#pragma unroll
            for (int r = 0; r < 4; ++r) {
                const int i = w * 16 + l4 * 4 + r;
                float val = 0.f;
                if (nt < w || (nt == w && jj <= i)) val = acc[r] * expf(gc[i] - gc[jj]);
                BB[16384 + i * 64 + (((jj >> 3) ^ (i & 7)) << 3) + (jj & 7)] = f2bf_rne(val);
            }
        }
        if ((h & 1) == 0) {
            u16* KB = bufK + (size_t)((n << 3) + hs) * 16384;
#pragma unroll
            for (int i = 0; i < 4; ++i) {
                int f = i * 256 + t;
                int c = f >> 4, sb = f & 15;
                *(uint4*)(KB + c * 128 + sb * 8) = *(const uint4*)(sQ + c * 128 + sb * 8);
            }
        }
    }
}

// ------------- Pass A: serial state recurrence, counted-vmcnt pipeline -------------
// 3 staging buffers (u16 each): U 0..8192 | kA 8192..16384 | ekd(64 f32) 16384..16512
// Per-chunk wave vmem ops: ckpt 4 (n>=1) + stage 9|8 + loadW 4 + eg<=1.
// vmcnt(20) at chunk-n top guarantees own stage(n) complete while stage(n+1) stays in flight.
#define STGA 16512

__global__ __launch_bounds__(256, 1) void scan_state_kernel(const u16* __restrict__ bufB,
                                                            const u16* __restrict__ bufK,
                                                            const float* __restrict__ ekd_g,
                                                            const float* __restrict__ eg_g,
                                                            u16* __restrict__ sstore) {
    __shared__ __align__(16) u16 sStage[3 * STGA];
    __shared__ __align__(16) u16 sSTb[4][16 * 136];
    __shared__ __align__(16) u16 sVTs[4][16 * 72];

    const int h = blockIdx.x >> 1;
    const int dvh = (blockIdx.x & 1) << 6;
    const int hs = h >> 1;
    const int w = threadIdx.x >> 6;
    const int l = threadIdx.x & 63;
    const int l15 = l & 15, l4 = l >> 4, l7 = l & 7;
    const int dv0 = dvh + (w << 4);

    u16* STb = sSTb[w];
    u16* VTs = sVTs[w];

    for (int i = l; i < 16 * 136; i += 64) STb[i] = 0;

    f32x4 Sreg[8];
#pragma unroll
    for (int i = 0; i < 8; ++i) Sreg[i] = (f32x4){0.f, 0.f, 0.f, 0.f};

    auto stage = [&](int n2, int slot) {
        u16* dst = sStage + slot * STGA;
        const int b2 = (n2 << 4) + h;
        const u16* sU = bufB + (size_t)b2 * 20480 + 8192 + w * 2048 + l * 8;
        u16* dU = dst + w * 2048;
#pragma unroll
        for (int i = 0; i < 4; ++i) gload_lds16(sU + i * 512, dU + i * 512);
        const u16* sKa = bufK + (size_t)((n2 << 3) + hs) * 16384 + 8192 + w * 2048 + l * 8;
        u16* dK = dst + 8192 + w * 2048;
#pragma unroll
        for (int i = 0; i < 4; ++i) gload_lds16(sKa + i * 512, dK + i * 512);
        if (w == 0) gload_lds4(ekd_g + (b2 << 6) + l, dst + 16384);
    };
    auto loadW = [&](int n2, uint2 (&wr)[4]) {
        const u16* wb = bufB + (size_t)((n2 << 4) + h) * 20480 + (size_t)(dv0 + l15) * 64 + l4 * 4;
#pragma unroll
        for (int mt = 0; mt < 4; ++mt) wr[mt] = *(const uint2*)(wb + mt * 16);
    };

    uint2 wA[4], wB[4];
    float egA, egB;
    // prologue: 2-deep fill
    stage(0, 0);
    stage(1, 1);
    loadW(0, wA);
    loadW(1, wB);
    egA = eg_g[h];
    egB = eg_g[16 + h];
    asm volatile("s_waitcnt vmcnt(16)" ::: "memory");   // own stage(0) complete
    __builtin_amdgcn_s_barrier();                        // all waves' stage(0) complete
    asm volatile("" ::: "memory");

    for (int n = 0; n < NCHUNK; ++n) {
        const u16* buf = sStage + (n % 3) * STGA;
        // top sync: own stage(n) done (issued 2 chunks ago), stage(n+1) stays in flight
        asm volatile("s_waitcnt vmcnt(20)" ::: "memory");
        __builtin_amdgcn_s_barrier();
        asm volatile("" ::: "memory");

        // checkpoint state n -> sstore[n] (never waited on inside this kernel)
        if (n > 0) {
            u16* dstg = sstore + ((size_t)(n * 16 + h)) * 16384 + (size_t)dv0 * 128;
#pragma unroll
            for (int i = 0; i < 4; ++i) {
                int idx = l * 4 + i;
                int row = idx >> 4, col = (idx & 15) << 3;
                *(uint4*)(dstg + row * 128 + col) = *(const uint4*)(STb + row * 136 + col);
            }
        }
        // issue next-next stage (slot (n+2)%3 is free: all waves passed barrier n) —
        // clamped at tail so per-chunk vmem counts stay uniform
        {
            int n2 = (n + 2 < NCHUNK) ? n + 2 : NCHUNK - 1;
            stage(n2, (n + 2) % 3);
        }
        uint2 wC[4];
        float egC;
        {
            int n2 = (n + 2 < NCHUNK) ? n + 2 : NCHUNK - 1;
            loadW(n2, wC);
            egC = eg_g[(n2 << 4) + h];
        }

        const u16* bU = buf;
        const u16* bK = buf + 8192;
        const float* ekd = (const float*)(buf + 16384);

        // state B-frags
        s16x8 bF[4];
#pragma unroll
        for (int kk = 0; kk < 4; ++kk)
            bF[kk] = *(const s16x8*)(STb + l15 * 136 + kk * 32 + l4 * 8);

        // V = W + (-U) @ S
        f32x4 V[4];
#pragma unroll
        for (int mt = 0; mt < 4; ++mt) {
            V[mt][0] = bfraw2f((u16)(wA[mt].x & 0xffffu));
            V[mt][1] = bfraw2f((u16)(wA[mt].x >> 16));
            V[mt][2] = bfraw2f((u16)(wA[mt].y & 0xffffu));
            V[mt][3] = bfraw2f((u16)(wA[mt].y >> 16));
        }
#pragma unroll
        for (int kk = 0; kk < 4; ++kk) {
            const int sw = ((kk * 4 + l4) ^ l7) << 3;
#pragma unroll
            for (int mt = 0; mt < 4; ++mt) {
                s16x8 a = *(const s16x8*)(bU + (mt * 16 + l15) * 128 + sw);
                V[mt] = __builtin_amdgcn_mfma_f32_16x16x32_bf16(a, bF[kk], V[mt], 0, 0, 0);
            }
        }

        // VTs = V^T * ekd[c]  (packed cvt on the serial path)
#pragma unroll
        for (int mt = 0; mt < 4; ++mt) {
            const int cb = mt * 16 + l4 * 4;
            uint2 us;
            us.x = pk_bf16(V[mt][0] * ekd[cb], V[mt][1] * ekd[cb + 1]);
            us.y = pk_bf16(V[mt][2] * ekd[cb + 2], V[mt][3] * ekd[cb + 3]);
            *(uint2*)(VTs + l15 * 72 + cb) = us;
        }

        // S = eg*S + kA @ VTs
        s16x8 sF0 = *(const s16x8*)(VTs + l15 * 72 + l4 * 8);
        s16x8 sF1 = *(const s16x8*)(VTs + l15 * 72 + 32 + l4 * 8);
#pragma unroll
        for (int nt = 0; nt < 8; ++nt) {
#pragma unroll
            for (int r = 0; r < 4; ++r) Sreg[nt][r] *= egA;
            s16x8 a0 = *(const s16x8*)(bK + (nt * 16 + l15) * 64 + ((l4 ^ l7) << 3));
            Sreg[nt] = __builtin_amdgcn_mfma_f32_16x16x32_bf16(a0, sF0, Sreg[nt], 0, 0, 0);
            s16x8 a1 = *(const s16x8*)(bK + (nt * 16 + l15) * 64 + (((4 + l4) ^ l7) << 3));
            Sreg[nt] = __builtin_amdgcn_mfma_f32_16x16x32_bf16(a1, sF1, Sreg[nt], 0, 0, 0);
        }
        // bf16 mirror for next chunk
#pragma unroll
        for (int nt = 0; nt < 8; ++nt) {
            uint2 sv;
            sv.x = pk_bf16(Sreg[nt][0], Sreg[nt][1]);
            sv.y = pk_bf16(Sreg[nt][2], Sreg[nt][3]);
            *(uint2*)(STb + l15 * 136 + nt * 16 + l4 * 4) = sv;
        }
#pragma unroll
        for (int i = 0; i < 4; ++i) { wA[i] = wB[i]; wB[i] = wC[i]; }
        egA = egB;
        egB = egC;
    }
}

// ------------- Pass B: parallel output computation (recompute V, O) -------------
// sStage (u16): U 0..8192 | Aqk 8192..12288 | qA 12288..20480 | egc(64 f32) 20480..20608
__global__ __launch_bounds__(512, 4) void scan_out_kernel(const u16* __restrict__ bufB,
                                                          const u16* __restrict__ bufK,
                                                          const u16* __restrict__ sstore,
                                                          const float* __restrict__ egc_g,
                                                          u16* __restrict__ o) {
    __shared__ __align__(16) u16 sStage[20608];
    __shared__ __align__(16) u16 sVT[8][16 * 72];

    const int bb = blockIdx.x;             // n*16 + h
    const int n = bb >> 4, h = bb & 15, hs = h >> 1;
    const int t = threadIdx.x;
    const int w = t >> 6, l = t & 63;
    const int l15 = l & 15, l4 = l >> 4, l7 = l & 7;
    const int dv0 = w << 4;
    u16* VT = sVT[w];

#pragma unroll
    for (int i = 0; i < 5; ++i) {
        int c = w + i * 8;
        if (c < 24)
            gload_lds16(bufB + (size_t)bb * 20480 + 8192 + c * 512 + l * 8, sStage + c * 512);
        else
            gload_lds16(bufK + (size_t)((n << 3) + hs) * 16384 + (c - 24) * 512 + l * 8,
                        sStage + 12288 + (c - 24) * 512);
    }
    if (w == 0) gload_lds4(egc_g + (bb << 6) + l, sStage + 20480);

    uint2 wr[4];
    {
        const u16* wb = bufB + (size_t)bb * 20480 + (size_t)(dv0 + l15) * 64 + l4 * 4;
#pragma unroll
        for (int mt = 0; mt < 4; ++mt) wr[mt] = *(const uint2*)(wb + mt * 16);
    }
    s16x8 bF[4];
    if (n > 0) {
        const u16* sp = sstore + (size_t)bb * 16384 + (size_t)(dv0 + l15) * 128 + l4 * 8;
#pragma unroll
        for (int kk = 0; kk < 4; ++kk)
            bF[kk] = *(const s16x8*)(sp + kk * 32);
    }
    __syncthreads();

    const u16* bU = sStage;
    const u16* bA = sStage + 8192;
    const u16* qA = sStage + 12288;
    const float* egc = (const float*)(sStage + 20480);

    f32x4 V[4];
#pragma unroll
    for (int mt = 0; mt < 4; ++mt) {
        V[mt][0] = bfraw2f((u16)(wr[mt].x & 0xffffu));
        V[mt][1] = bfraw2f((u16)(wr[mt].x >> 16));
        V[mt][2] = bfraw2f((u16)(wr[mt].y & 0xffffu));
        V[mt][3] = bfraw2f((u16)(wr[mt].y >> 16));
    }
    f32x4 O[4];
#pragma unroll
    for (int mt = 0; mt < 4; ++mt) O[mt] = (f32x4){0.f, 0.f, 0.f, 0.f};
    if (n > 0) {
#pragma unroll
        for (int kk = 0; kk < 4; ++kk) {
            const int sw = ((kk * 4 + l4) ^ l7) << 3;
#pragma unroll
            for (int mt = 0; mt < 4; ++mt) {
                s16x8 a = *(const s16x8*)(bU + (mt * 16 + l15) * 128 + sw);
                V[mt] = __builtin_amdgcn_mfma_f32_16x16x32_bf16(a, bF[kk], V[mt], 0, 0, 0);
            }
        }
#pragma unroll
        for (int kk = 0; kk < 4; ++kk) {
            const int sw = ((kk * 4 + l4) ^ l7) << 3;
#pragma unroll
            for (int mt = 0; mt < 4; ++mt) {
                s16x8 a = *(const s16x8*)(qA + (mt * 16 + l15) * 128 + sw);
                O[mt] = __builtin_amdgcn_mfma_f32_16x16x32_bf16(a, bF[kk], O[mt], 0, 0, 0);
            }
        }
#pragma unroll
        for (int mt = 0; mt < 4; ++mt)
#pragma unroll
            for (int r = 0; r < 4; ++r) O[mt][r] *= egc[mt * 16 + l4 * 4 + r];
    }

#pragma unroll
    for (int mt = 0; mt < 4; ++mt) {
        const int cb = mt * 16 + l4 * 4;
        uint2 uv;
        uv.x = (u32)f2bf_rne(V[mt][0]) | ((u32)f2bf_rne(V[mt][1]) << 16);
        uv.y = (u32)f2bf_rne(V[mt][2]) | ((u32)f2bf_rne(V[mt][3]) << 16);
        *(uint2*)(VT + l15 * 72 + cb) = uv;
    }
    s16x8 vF0 = *(const s16x8*)(VT + l15 * 72 + l4 * 8);
    s16x8 vF1 = *(const s16x8*)(VT + l15 * 72 + 32 + l4 * 8);
#pragma unroll
    for (int mt = 0; mt < 4; ++mt) {
        s16x8 a = *(const s16x8*)(bA + (mt * 16 + l15) * 64 + ((l4 ^ l7) << 3));
        O[mt] = __builtin_amdgcn_mfma_f32_16x16x32_bf16(a, vF0, O[mt], 0, 0, 0);
    }
#pragma unroll
    for (int mt = 0; mt < 4; ++mt) {
        s16x8 a = *(const s16x8*)(bA + (mt * 16 + l15) * 64 + (((4 + l4) ^ l7) << 3));
        O[mt] = __builtin_amdgcn_mfma_f32_16x16x32_bf16(a, vF1, O[mt], 0, 0, 0);
    }

    const int s0 = n << 6;
#pragma unroll
    for (int mt = 0; mt < 4; ++mt)
#pragma unroll
        for (int r = 0; r < 4; ++r)
            o[(size_t)(s0 + mt * 16 + l4 * 4 + r) * 2048 + (h << 7) + dv0 + l15] = f2bf_rne(O[mt][r]);
}

// ------------- gated rmsnorm * silu(z) -> bf16 -------------
__global__ __launch_bounds__(256) void gate_kernel(const u16* __restrict__ o,
                                                   const u16* __restrict__ Cz,
                                                   const float* __restrict__ norm_w,
                                                   u16* __restrict__ gated) {
    const int s = blockIdx.x, t = threadIdx.x;
    const int c8 = t << 3, hh = t >> 4;
    __shared__ float ssq[16];
    if (t < 16) ssq[t] = 0.f;
    float ov[8];
    unpack8(*(const uint4*)(o + (size_t)s * 2048 + c8), ov);
    float p = 0.f;
#pragma unroll
    for (int i = 0; i < 8; ++i) p += ov[i] * ov[i];
    __syncthreads();
    atomicAdd(&ssq[hh], p);
    __syncthreads();
    const float rms = rsqrtf(ssq[hh] * 0.0078125f + EPSF);
    float zf[8];
    unpack8(*(const uint4*)(Cz + (size_t)s * 2048 + c8), zf);
    const int d0 = c8 & 127;
    float res[8];
#pragma unroll
    for (int i = 0; i < 8; ++i) {
        float z = zf[i];
        float sz = z / (1.f + expf(-z));
        res[i] = ov[i] * rms * norm_w[d0 + i] * sz;
    }
    *(uint4*)(gated + (size_t)s * 2048 + c8) = pack8(res);
}

extern "C" void kernel_launch(void* const* d_in, const int* in_sizes, int n_in,
                              void* d_out, int out_size, void* d_ws, size_t ws_size,
                              hipStream_t stream) {
    (void)in_sizes; (void)n_in; (void)out_size; (void)ws_size;
    const float* x       = (const float*)d_in[0];
    const float* W_qkv   = (const float*)d_in[1];
    const float* W_z     = (const float*)d_in[2];
    const float* W_b     = (const float*)d_in[3];
    const float* W_a     = (const float*)d_in[4];
    const float* conv_w  = (const float*)d_in[5];
    const float* A_log   = (const float*)d_in[6];
    const float* dt_bias = (const float*)d_in[7];
    const float* norm_w  = (const float*)d_in[8];
    const float* W_out   = (const float*)d_in[9];

    char* p = (char*)d_ws;
    auto alloc = [&](size_t bytes) {
        char* r = p;
        p += (bytes + 255) & ~(size_t)255;
        return r;
    };
    u16* Cmix    = (u16*)alloc((size_t)S_LEN * NQKV * 2);       // 67.1 MB (dead after prep)
    char* extra  = alloc((size_t)50331648); (void)extra;        // 50.3 MB (bufB/bufK tail)
    u16* qn      = (u16*)alloc((size_t)S_LEN * HKN * DKD * 2);  // 16.8 MB
    u16* kn      = (u16*)alloc((size_t)S_LEN * HKN * DKD * 2);  // 16.8 MB
    u16* vb      = (u16*)alloc((size_t)S_LEN * HVN * DVD * 2);  // 33.5 MB
    float* egc   = (float*)alloc((size_t)NCHUNK * HVN * CLEN * 4);
    float* ekd   = (float*)alloc((size_t)NCHUNK * HVN * CLEN * 4);
    float* eg    = (float*)alloc((size_t)NCHUNK * HVN * 4);
    float* beta  = (float*)alloc((size_t)S_LEN * HVN * 4);
    float* g     = (float*)alloc((size_t)S_LEN * HVN * 4);
    // lifetime-disjoint overlays:
    u16* bufB  = Cmix;
    u16* bufK  = (u16*)((char*)Cmix + (size_t)83886080);
    u16* o_buf = qn;
    u16* Cz    = vb;
    u16* gated = Cmix;
    // scratch inside d_out (dead before final GEMM writes d_out):
    u16* xbf    = (u16*)d_out;
    u16* Wq_t   = (u16*)d_out + (size_t)16777216;
    u16* Wz_t   = (u16*)d_out + (size_t)25165824;
    u16* sstore = (u16*)d_out;                       // 2048 x 16384 u16 = 67.1 MB (exact fit)
    u16* Wout_t = qn;

    ba_kernel<<<S_LEN / 8, 256, 0, stream>>>(x, W_b, W_a, A_log, dt_bias, beta, g);
    cvt_x_kernel<<<S_LEN * HID / (256 * 8), 256, 0, stream>>>(x, xbf);
    cvt_wT_kernel<<<dim3(NQKV / 64, HID / 64), 256, 0, stream>>>(W_qkv, Wq_t, NQKV, HID);
    cvt_wT_kernel<<<dim3(HID / 64, HID / 64), 256, 0, stream>>>(W_z, Wz_t, HID, HID);
    gemm_bt<0><<<dim3(NQKV / 128, S_LEN / 128), 256, 0, stream>>>(xbf, Wq_t, Cmix, S_LEN, NQKV, HID);
    prep_kernel<<<S_LEN, 512, 0, stream>>>(Cmix, conv_w, beta, qn, kn, vb);
    precomp_kernel<<<NCHUNK * HVN, 256, 0, stream>>>(qn, kn, vb, g, beta, bufB, bufK, egc, ekd, eg);
    gemm_bt<0><<<dim3(HID / 128, S_LEN / 128), 256, 0, stream>>>(xbf, Wz_t, Cz, S_LEN, HID, HID);
    // Pass A: serial recurrence + checkpoints (sstore over dead xbf/Wq_t/Wz_t in d_out)
    scan_state_kernel<<<HVN * 2, 256, 0, stream>>>(bufB, bufK, ekd, eg, sstore);
    // Pass B: parallel output computation
    scan_out_kernel<<<NCHUNK * HVN, 512, 0, stream>>>(bufB, bufK, sstore, egc, o_buf);
    gate_kernel<<<S_LEN, 256, 0, stream>>>(o_buf, Cz, norm_w, gated);
    cvt_wT_kernel<<<dim3(HID / 64, HID / 64), 256, 0, stream>>>(W_out, Wout_t, HID, HID);
    gemm_bt<1><<<dim3(HID / 128, S_LEN / 128), 256, 0, stream>>>(gated, Wout_t, d_out, S_LEN, HID, HID);
}